// Round 1
// baseline (2901.975 us; speedup 1.0000x reference)
//
#include <hip/hip_runtime.h>
#include <cmath>

// CfC-NCP RNN, phase-decomposed:
//   per chunk c (TC=128 steps): x0 (parallel GEMM x->XU0), r0 (recurrent layer0,
//   weights resident in VGPRs, 16 WGs = 16 batch tiles), x1 (parallel GEMM nh0->XU1),
//   r12 (recurrent layer1 on waves 0-6 + layer2 on wave 7, half-step skewed).
// fp16 MFMA inputs, fp32 accum. Workspace ~78 MB.

typedef _Float16 f16;
typedef f16 h4 __attribute__((ext_vector_type(4)));
typedef f16 h8 __attribute__((ext_vector_type(8)));
typedef float f4 __attribute__((ext_vector_type(4)));

#define MFMA(a, b, c) __builtin_amdgcn_mfma_f32_16x16x32_f16(a, b, c, 0, 0, 0)

constexpr int IN_DIM = 128, Ni = 149, Nc = 99, Nm = 8;
constexpr int CAT0 = 277, CAT1 = 248, CAT2 = 107;
constexpr int Bsz = 256, Tsz = 512;
constexpr int TC = 128, NCH = 4, NBT = 16;
constexpr int NT0 = 40, NT1 = 28;        // fragment tile-columns (4 mats x n-tiles)
constexpr int S0 = 168, S2 = 136;        // LDS row strides (halves), bank-conflict pad
constexpr size_t XU0_HALVES = (size_t)TC * NBT * NT0 * 256;  // 20,971,520
constexpr size_t NH0_HALVES = (size_t)TC * NBT * 16 * 160;   //  5,242,880
constexpr size_t XU1_HALVES = (size_t)TC * NBT * NT1 * 256;  // 14,680,064
constexpr size_t H0S_HALVES = (size_t)NBT * 16 * S0;
constexpr size_t H12S_HALVES = (size_t)NBT * 2 * 16 * S2;
constexpr size_t YOFF = (size_t)Bsz * Tsz * 8;  // h_out offset in d_out

__device__ inline float rcpf_(float x) { return __builtin_amdgcn_rcpf(x); }
__device__ inline float tanhf_(float x) {
  float e = __expf(-2.f * fabsf(x));          // in (0,1], no overflow
  float t = (1.f - e) * rcpf_(1.f + e);
  return x < 0.f ? -t : t;
}
__device__ inline float sigm_(float z) { return rcpf_(1.f + __expf(-z)); }

// B-fragment loader: lane holds B[k = k0..k0+7][n], n = per-lane row of W (out = xh @ W^T).
__device__ inline h8 bfrag(const float* W, const int* M, int ld, int n, int nmax,
                           int k0, int kmax) {
  h8 r;
#pragma unroll
  for (int j = 0; j < 8; j++) {
    int k = k0 + j;
    float v = 0.f;
    if (n < nmax && k < kmax) {
      v = W[(size_t)n * ld + k];
      if (M) v *= (float)M[(size_t)n * ld + k];
    }
    r[j] = (f16)v;
  }
  return r;
}

// ---------------- x0: XU0[mt, mat*10+nt, frag] = x(t) @ Wx0^T (masked w1,w2) ---------
__global__ __launch_bounds__(256, 2) void x0_kernel(
    const float* __restrict__ w1, const float* __restrict__ w2,
    const float* __restrict__ wa, const float* __restrict__ wb,
    const int* __restrict__ m0, const float* __restrict__ x,
    f16* __restrict__ XU0, int c) {
  __shared__ f16 stg[16 * 136];
  int tid = threadIdx.x;
  int w = tid >> 6, lane = tid & 63, col = lane & 15, q = lane >> 4;
  const float* Ws[4] = {w1, w2, wa, wb};
  const float* W = Ws[w];
  const int* Mp = (w < 2) ? m0 : nullptr;
  h8 Bf[10][4];
#pragma unroll
  for (int nt = 0; nt < 10; nt++)
#pragma unroll
    for (int kt = 0; kt < 4; kt++)
      Bf[nt][kt] = bfrag(W, Mp, CAT0, nt * 16 + col, Ni, kt * 32 + q * 8, IN_DIM);

  int sr = tid >> 4, sc = (tid & 15) * 8;
  for (int i = 0; i < 4; i++) {
    int mt = blockIdx.x * 4 + i;          // 0..2047 = t_local*16 + bt
    int tl = mt >> 4, bt = mt & 15;
    int tg = c * TC + tl;
    const float* xp = x + ((size_t)(bt * 16 + sr) * Tsz + tg) * IN_DIM + sc;
    h8 hv;
#pragma unroll
    for (int j = 0; j < 8; j++) hv[j] = (f16)xp[j];
    *(h8*)(stg + sr * 136 + sc) = hv;
    __syncthreads();
    h8 A[4];
#pragma unroll
    for (int kt = 0; kt < 4; kt++)
      A[kt] = *(const h8*)(stg + col * 136 + kt * 32 + q * 8);
#pragma unroll
    for (int nt = 0; nt < 10; nt++) {
      f4 acc = {0.f, 0.f, 0.f, 0.f};
#pragma unroll
      for (int kt = 0; kt < 4; kt++) acc = MFMA(A[kt], Bf[nt][kt], acc);
      h4 o;
#pragma unroll
      for (int rr = 0; rr < 4; rr++) o[rr] = (f16)acc[rr];
      *(h4*)(XU0 + ((size_t)mt * NT0 + w * 10 + nt) * 256 + lane * 4) = o;
    }
    __syncthreads();
  }
}

// ---------------- x1: XU1[mt, mat*7+nt, frag] = nh0(t) @ Wx1^T (masked w1,w2) --------
__global__ __launch_bounds__(256, 2) void x1_kernel(
    const float* __restrict__ w1, const float* __restrict__ w2,
    const float* __restrict__ wa, const float* __restrict__ wb,
    const int* __restrict__ m1, const f16* __restrict__ NH0,
    f16* __restrict__ XU1) {
  int tid = threadIdx.x;
  int w = tid >> 6, lane = tid & 63, col = lane & 15, q = lane >> 4;
  const float* Ws[4] = {w1, w2, wa, wb};
  const float* W = Ws[w];
  const int* Mp = (w < 2) ? m1 : nullptr;
  h8 Bf[7][5];
#pragma unroll
  for (int nt = 0; nt < 7; nt++)
#pragma unroll
    for (int kt = 0; kt < 5; kt++)
      Bf[nt][kt] = bfrag(W, Mp, CAT1, nt * 16 + col, Nc, kt * 32 + q * 8, Ni);
  for (int i = 0; i < 4; i++) {
    int mt = blockIdx.x * 4 + i;
    const f16* Ab = NH0 + (size_t)mt * 2560;  // 16 x 160 halves, pad cols hit zero B-rows
    h8 A[5];
#pragma unroll
    for (int kt = 0; kt < 5; kt++)
      A[kt] = *(const h8*)(Ab + col * 160 + kt * 32 + q * 8);
#pragma unroll
    for (int nt = 0; nt < 7; nt++) {
      f4 acc = {0.f, 0.f, 0.f, 0.f};
#pragma unroll
      for (int kt = 0; kt < 5; kt++) acc = MFMA(A[kt], Bf[nt][kt], acc);
      h4 o;
#pragma unroll
      for (int rr = 0; rr < 4; rr++) o[rr] = (f16)acc[rr];
      *(h4*)(XU1 + ((size_t)mt * NT1 + w * 7 + nt) * 256 + lane * 4) = o;
    }
  }
}

// ---------------- r0: sequential layer-0 recurrence, 16 WGs x 640 thr (10 waves) -----
__global__ __launch_bounds__(640, 3) void r0_kernel(
    const float* __restrict__ w1, const float* __restrict__ w2,
    const float* __restrict__ wa, const float* __restrict__ wb,
    const float* __restrict__ b1, const float* __restrict__ b2,
    const float* __restrict__ ba, const float* __restrict__ bb,
    const float* __restrict__ dtp, const f16* __restrict__ XU0,
    f16* __restrict__ NH0, f16* __restrict__ H0S, float* __restrict__ out, int c) {
  __shared__ f16 buf[2][16 * S0];
  int tid = threadIdx.x;
  int g = tid >> 6, lane = tid & 63, col = lane & 15, q = lane >> 4;
  int bt = blockIdx.x;
  int n = g * 16 + col;                      // output neuron (0..159, valid <149)
  float ts = dtp[0];
  const float* Ws[4] = {w1, w2, wa, wb};
  h8 Bf[4][5];                               // recurrent weights, resident across t-loop
#pragma unroll
  for (int mat = 0; mat < 4; mat++)
#pragma unroll
    for (int kt = 0; kt < 5; kt++)
      Bf[mat][kt] = bfrag(Ws[mat], nullptr, CAT0, n, Ni, IN_DIM + kt * 32 + q * 8, CAT0);
  float b1n = (n < Ni) ? b1[n] : 0.f, b2n = (n < Ni) ? b2[n] : 0.f;
  float ban = (n < Ni) ? ba[n] : 0.f, bbn = (n < Ni) ? bb[n] : 0.f;

  for (int idx = tid; idx < 16 * S0; idx += 640) {
    buf[0][idx] = (c == 0) ? (f16)0.f : H0S[(size_t)bt * 16 * S0 + idx];
    buf[1][idx] = (f16)0.f;
  }
  __syncthreads();

  for (int t = 0; t < TC; t++) {
    const f16* br = buf[t & 1];
    f16* bw = buf[(t + 1) & 1];
    int mt = t * NBT + bt;
    h4 xuv[4];
#pragma unroll
    for (int mat = 0; mat < 4; mat++)
      xuv[mat] = *(const h4*)(XU0 + ((size_t)mt * NT0 + mat * 10 + g) * 256 + lane * 4);
    h8 A[5];
#pragma unroll
    for (int kt = 0; kt < 5; kt++)
      A[kt] = *(const h8*)(br + col * S0 + kt * 32 + q * 8);
    f4 acc[4];
#pragma unroll
    for (int mat = 0; mat < 4; mat++) acc[mat] = (f4){0.f, 0.f, 0.f, 0.f};
#pragma unroll
    for (int kt = 0; kt < 5; kt++)
#pragma unroll
      for (int mat = 0; mat < 4; mat++)
        acc[mat] = MFMA(A[kt], Bf[mat][kt], acc[mat]);
    f16* nh = NH0 + (size_t)mt * 2560;
#pragma unroll
    for (int r = 0; r < 4; r++) {
      int m = q * 4 + r;
      float u1 = acc[0][r] + (float)xuv[0][r] + b1n;
      float u2 = acc[1][r] + (float)xuv[1][r] + b2n;
      float ua = acc[2][r] + (float)xuv[2][r] + ban;
      float ub = acc[3][r] + (float)xuv[3][r] + bbn;
      float ff1 = tanhf_(u1), ff2 = tanhf_(u2);
      float ti = sigm_(ua * ts + ub);
      float h = ff1 + (ff2 - ff1) * ti;
      f16 h16 = (f16)h;
      bw[m * S0 + n] = h16;
      nh[m * 160 + n] = h16;
      if (c == NCH - 1 && t == TC - 1 && n < Ni)
        out[YOFF + (size_t)(bt * 16 + m) * 256 + n] = h;
    }
    __syncthreads();
  }
  for (int idx = tid; idx < 16 * S0; idx += 640)
    H0S[(size_t)bt * 16 * S0 + idx] = buf[0][idx];
}

// ---------------- r12: layer1 (waves 0-6) + layer2 (wave 7, half-step skew) ----------
__global__ __launch_bounds__(512, 2) void r12_kernel(
    const float* __restrict__ w1, const float* __restrict__ w2,
    const float* __restrict__ wa, const float* __restrict__ wb,
    const float* __restrict__ b1, const float* __restrict__ b2,
    const float* __restrict__ ba, const float* __restrict__ bb,
    const float* __restrict__ v1, const float* __restrict__ v2,
    const float* __restrict__ va, const float* __restrict__ vb,
    const float* __restrict__ c1, const float* __restrict__ c2,
    const float* __restrict__ ca, const float* __restrict__ cb,
    const int* __restrict__ m2, const float* __restrict__ dtp,
    const f16* __restrict__ XU1, f16* __restrict__ H12S,
    float* __restrict__ out, int c) {
  __shared__ f16 buf[2][16 * S2];  // [nh1(0..98) | h2(99..106) | pad]; B rows k>=99 are 0
  int tid = threadIdx.x;
  int w = tid >> 6, lane = tid & 63, col = lane & 15, q = lane >> 4;
  int bt = blockIdx.x;
  float ts = dtp[0];
  h8 Bf[4][4];
  float bn[4];
  if (w < 7) {
    const float* Ws[4] = {w1, w2, wa, wb};
    int n = w * 16 + col;
#pragma unroll
    for (int mat = 0; mat < 4; mat++)
#pragma unroll
      for (int kt = 0; kt < 4; kt++)
        Bf[mat][kt] = bfrag(Ws[mat], nullptr, CAT1, n, Nc, Ni + kt * 32 + q * 8, CAT1);
    bn[0] = (n < Nc) ? b1[n] : 0.f;
    bn[1] = (n < Nc) ? b2[n] : 0.f;
    bn[2] = (n < Nc) ? ba[n] : 0.f;
    bn[3] = (n < Nc) ? bb[n] : 0.f;
  } else {
    const float* Ws[4] = {v1, v2, va, vb};
#pragma unroll
    for (int mat = 0; mat < 4; mat++)
#pragma unroll
      for (int kt = 0; kt < 4; kt++)
        Bf[mat][kt] = bfrag(Ws[mat], (mat < 2) ? m2 : nullptr, CAT2, col, Nm,
                            kt * 32 + q * 8, CAT2);
    bn[0] = (col < Nm) ? c1[col] : 0.f;
    bn[1] = (col < Nm) ? c2[col] : 0.f;
    bn[2] = (col < Nm) ? ca[col] : 0.f;
    bn[3] = (col < Nm) ? cb[col] : 0.f;
  }
  for (int idx = tid; idx < 2 * 16 * S2; idx += 512)
    ((f16*)buf)[idx] = (c == 0) ? (f16)0.f : H12S[(size_t)bt * 2 * 16 * S2 + idx];
  __syncthreads();

  for (int t = 0; t < TC; t++) {
    f16* br = buf[t & 1];
    f16* bw = buf[(t + 1) & 1];
    if (w < 7) {
      int mt = t * NBT + bt;
      int n = w * 16 + col;
      h4 xuv[4];
#pragma unroll
      for (int mat = 0; mat < 4; mat++)
        xuv[mat] =
            *(const h4*)(XU1 + ((size_t)mt * NT1 + mat * 7 + w) * 256 + lane * 4);
      h8 A[4];
#pragma unroll
      for (int kt = 0; kt < 4; kt++)
        A[kt] = *(const h8*)(br + col * S2 + kt * 32 + q * 8);
      f4 acc[4];
#pragma unroll
      for (int mat = 0; mat < 4; mat++) acc[mat] = (f4){0.f, 0.f, 0.f, 0.f};
#pragma unroll
      for (int kt = 0; kt < 4; kt++)
#pragma unroll
        for (int mat = 0; mat < 4; mat++)
          acc[mat] = MFMA(A[kt], Bf[mat][kt], acc[mat]);
#pragma unroll
      for (int r = 0; r < 4; r++) {
        int m = q * 4 + r;
        float u1 = acc[0][r] + (float)xuv[0][r] + bn[0];
        float u2 = acc[1][r] + (float)xuv[1][r] + bn[1];
        float ua = acc[2][r] + (float)xuv[2][r] + bn[2];
        float ub = acc[3][r] + (float)xuv[3][r] + bn[3];
        float ff1 = tanhf_(u1), ff2 = tanhf_(u2);
        float ti = sigm_(ua * ts + ub);
        float h = ff1 + (ff2 - ff1) * ti;
        if (n < Nc) {
          bw[m * S2 + n] = (f16)h;
          if (c == NCH - 1 && t == TC - 1)
            out[YOFF + (size_t)(bt * 16 + m) * 256 + Ni + n] = h;
        }
      }
    }
    __syncthreads();
    if (w == 7) {  // layer2(t): A = [nh1(t) | h2(t-1)] in bw; writes h2(t) into br
      int tg = c * TC + t;
      h8 A[4];
#pragma unroll
      for (int kt = 0; kt < 4; kt++)
        A[kt] = *(const h8*)(bw + col * S2 + kt * 32 + q * 8);
      f4 acc[4];
#pragma unroll
      for (int mat = 0; mat < 4; mat++) acc[mat] = (f4){0.f, 0.f, 0.f, 0.f};
#pragma unroll
      for (int kt = 0; kt < 4; kt++)
#pragma unroll
        for (int mat = 0; mat < 4; mat++)
          acc[mat] = MFMA(A[kt], Bf[mat][kt], acc[mat]);
#pragma unroll
      for (int r = 0; r < 4; r++) {
        int m = q * 4 + r;
        float u1 = acc[0][r] + bn[0];
        float u2 = acc[1][r] + bn[1];
        float ua = acc[2][r] + bn[2];
        float ub = acc[3][r] + bn[3];
        float ff1 = tanhf_(u1), ff2 = tanhf_(u2);
        float ti = sigm_(ua * ts + ub);
        float h = ff1 + (ff2 - ff1) * ti;
        if (col < Nm) {
          out[((size_t)(bt * 16 + m) * Tsz + tg) * 8 + col] = tanhf_(h);
          br[m * S2 + Nc + col] = (f16)h;
          if (c == NCH - 1 && t == TC - 1)
            out[YOFF + (size_t)(bt * 16 + m) * 256 + Ni + Nc + col] = h;
        }
      }
    }
  }
  __syncthreads();
  for (int idx = tid; idx < 2 * 16 * S2; idx += 512)
    H12S[(size_t)bt * 2 * 16 * S2 + idx] = ((f16*)buf)[idx];
}

extern "C" void kernel_launch(void* const* d_in, const int* in_sizes, int n_in,
                              void* d_out, int out_size, void* d_ws, size_t ws_size,
                              hipStream_t stream) {
  const float* w1_0 = (const float*)d_in[0];
  const float* w2_0 = (const float*)d_in[1];
  const float* wa_0 = (const float*)d_in[2];
  const float* wb_0 = (const float*)d_in[3];
  const float* b1_0 = (const float*)d_in[4];
  const float* b2_0 = (const float*)d_in[5];
  const float* ba_0 = (const float*)d_in[6];
  const float* bb_0 = (const float*)d_in[7];
  const int* m0 = (const int*)d_in[8];
  const float* w1_1 = (const float*)d_in[9];
  const float* w2_1 = (const float*)d_in[10];
  const float* wa_1 = (const float*)d_in[11];
  const float* wb_1 = (const float*)d_in[12];
  const float* b1_1 = (const float*)d_in[13];
  const float* b2_1 = (const float*)d_in[14];
  const float* ba_1 = (const float*)d_in[15];
  const float* bb_1 = (const float*)d_in[16];
  const int* m1 = (const int*)d_in[17];
  const float* w1_2 = (const float*)d_in[18];
  const float* w2_2 = (const float*)d_in[19];
  const float* wa_2 = (const float*)d_in[20];
  const float* wb_2 = (const float*)d_in[21];
  const float* c1 = (const float*)d_in[22];
  const float* c2 = (const float*)d_in[23];
  const float* ca = (const float*)d_in[24];
  const float* cb = (const float*)d_in[25];
  const int* m2 = (const int*)d_in[26];
  const float* x = (const float*)d_in[27];
  const float* dt = (const float*)d_in[28];
  float* out = (float*)d_out;

  f16* XU0 = (f16*)d_ws;
  f16* NH0 = XU0 + XU0_HALVES;
  f16* XU1 = NH0 + NH0_HALVES;
  f16* H0S = XU1 + XU1_HALVES;
  f16* H12S = H0S + H0S_HALVES;

  for (int c = 0; c < NCH; c++) {
    x0_kernel<<<512, 256, 0, stream>>>(w1_0, w2_0, wa_0, wb_0, m0, x, XU0, c);
    r0_kernel<<<16, 640, 0, stream>>>(w1_0, w2_0, wa_0, wb_0, b1_0, b2_0, ba_0, bb_0,
                                      dt, XU0, NH0, H0S, out, c);
    x1_kernel<<<512, 256, 0, stream>>>(w1_1, w2_1, wa_1, wb_1, m1, NH0, XU1);
    r12_kernel<<<16, 512, 0, stream>>>(w1_1, w2_1, wa_1, wb_1, b1_1, b2_1, ba_1, bb_1,
                                       w1_2, w2_2, wa_2, wb_2, c1, c2, ca, cb, m2, dt,
                                       XU1, H12S, out, c);
  }
}

// Round 2
// 2741.405 us; speedup vs baseline: 1.0586x; 1.0586x over previous
//
#include <hip/hip_runtime.h>
#include <cmath>

// CfC-NCP RNN, phase-decomposed:
//   per chunk c (TC=128 steps): x0 (parallel GEMM x->XU0), r0 (recurrent layer0,
//   weights resident in VGPRs, 16 WGs = 16 batch tiles), x1 (parallel GEMM nh0->XU1),
//   r12 (recurrent layer1 on waves 0-6 + layer2 on wave 7, half-step skewed).
// fp16 MFMA inputs, fp32 accum. Workspace ~78 MB.
// R1: latency fixes in r0/r12 — XU prefetch 1 step ahead (global-load latency off the
// critical path) + raw "s_waitcnt lgkmcnt(0); s_barrier" in the hot loop (avoids the
// compiler's vmcnt(0) drain of in-flight global loads/stores at every __syncthreads).

typedef _Float16 f16;
typedef f16 h4 __attribute__((ext_vector_type(4)));
typedef f16 h8 __attribute__((ext_vector_type(8)));
typedef float f4 __attribute__((ext_vector_type(4)));

#define MFMA(a, b, c) __builtin_amdgcn_mfma_f32_16x16x32_f16(a, b, c, 0, 0, 0)
// LDS-only barrier: waves drain their own LDS ops (lgkmcnt) then sync; global ops
// (XU prefetch loads, NH0/y stores) intentionally left in flight.
#define RAW_BAR() asm volatile("s_waitcnt lgkmcnt(0)\n\ts_barrier" ::: "memory")

constexpr int IN_DIM = 128, Ni = 149, Nc = 99, Nm = 8;
constexpr int CAT0 = 277, CAT1 = 248, CAT2 = 107;
constexpr int Bsz = 256, Tsz = 512;
constexpr int TC = 128, NCH = 4, NBT = 16;
constexpr int NT0 = 40, NT1 = 28;        // fragment tile-columns (4 mats x n-tiles)
constexpr int S0 = 168, S2 = 136;        // LDS row strides (halves), bank-conflict pad
constexpr size_t XU0_HALVES = (size_t)TC * NBT * NT0 * 256;  // 20,971,520
constexpr size_t NH0_HALVES = (size_t)TC * NBT * 16 * 160;   //  5,242,880
constexpr size_t XU1_HALVES = (size_t)TC * NBT * NT1 * 256;  // 14,680,064
constexpr size_t H0S_HALVES = (size_t)NBT * 16 * S0;
constexpr size_t H12S_HALVES = (size_t)NBT * 2 * 16 * S2;
constexpr size_t YOFF = (size_t)Bsz * Tsz * 8;  // h_out offset in d_out

__device__ inline float rcpf_(float x) { return __builtin_amdgcn_rcpf(x); }
__device__ inline float tanhf_(float x) {
  float e = __expf(-2.f * fabsf(x));          // in (0,1], no overflow
  float t = (1.f - e) * rcpf_(1.f + e);
  return x < 0.f ? -t : t;
}
__device__ inline float sigm_(float z) { return rcpf_(1.f + __expf(-z)); }

// B-fragment loader: lane holds B[k = k0..k0+7][n], n = per-lane row of W (out = xh @ W^T).
__device__ inline h8 bfrag(const float* W, const int* M, int ld, int n, int nmax,
                           int k0, int kmax) {
  h8 r;
#pragma unroll
  for (int j = 0; j < 8; j++) {
    int k = k0 + j;
    float v = 0.f;
    if (n < nmax && k < kmax) {
      v = W[(size_t)n * ld + k];
      if (M) v *= (float)M[(size_t)n * ld + k];
    }
    r[j] = (f16)v;
  }
  return r;
}

// ---------------- x0: XU0[mt, mat*10+nt, frag] = x(t) @ Wx0^T (masked w1,w2) ---------
__global__ __launch_bounds__(256, 2) void x0_kernel(
    const float* __restrict__ w1, const float* __restrict__ w2,
    const float* __restrict__ wa, const float* __restrict__ wb,
    const int* __restrict__ m0, const float* __restrict__ x,
    f16* __restrict__ XU0, int c) {
  __shared__ f16 stg[16 * 136];
  int tid = threadIdx.x;
  int w = tid >> 6, lane = tid & 63, col = lane & 15, q = lane >> 4;
  const float* Ws[4] = {w1, w2, wa, wb};
  const float* W = Ws[w];
  const int* Mp = (w < 2) ? m0 : nullptr;
  h8 Bf[10][4];
#pragma unroll
  for (int nt = 0; nt < 10; nt++)
#pragma unroll
    for (int kt = 0; kt < 4; kt++)
      Bf[nt][kt] = bfrag(W, Mp, CAT0, nt * 16 + col, Ni, kt * 32 + q * 8, IN_DIM);

  int sr = tid >> 4, sc = (tid & 15) * 8;
  for (int i = 0; i < 4; i++) {
    int mt = blockIdx.x * 4 + i;          // 0..2047 = t_local*16 + bt
    int tl = mt >> 4, bt = mt & 15;
    int tg = c * TC + tl;
    const float* xp = x + ((size_t)(bt * 16 + sr) * Tsz + tg) * IN_DIM + sc;
    h8 hv;
#pragma unroll
    for (int j = 0; j < 8; j++) hv[j] = (f16)xp[j];
    *(h8*)(stg + sr * 136 + sc) = hv;
    __syncthreads();
    h8 A[4];
#pragma unroll
    for (int kt = 0; kt < 4; kt++)
      A[kt] = *(const h8*)(stg + col * 136 + kt * 32 + q * 8);
#pragma unroll
    for (int nt = 0; nt < 10; nt++) {
      f4 acc = {0.f, 0.f, 0.f, 0.f};
#pragma unroll
      for (int kt = 0; kt < 4; kt++) acc = MFMA(A[kt], Bf[nt][kt], acc);
      h4 o;
#pragma unroll
      for (int rr = 0; rr < 4; rr++) o[rr] = (f16)acc[rr];
      *(h4*)(XU0 + ((size_t)mt * NT0 + w * 10 + nt) * 256 + lane * 4) = o;
    }
    __syncthreads();
  }
}

// ---------------- x1: XU1[mt, mat*7+nt, frag] = nh0(t) @ Wx1^T (masked w1,w2) --------
__global__ __launch_bounds__(256, 2) void x1_kernel(
    const float* __restrict__ w1, const float* __restrict__ w2,
    const float* __restrict__ wa, const float* __restrict__ wb,
    const int* __restrict__ m1, const f16* __restrict__ NH0,
    f16* __restrict__ XU1) {
  int tid = threadIdx.x;
  int w = tid >> 6, lane = tid & 63, col = lane & 15, q = lane >> 4;
  const float* Ws[4] = {w1, w2, wa, wb};
  const float* W = Ws[w];
  const int* Mp = (w < 2) ? m1 : nullptr;
  h8 Bf[7][5];
#pragma unroll
  for (int nt = 0; nt < 7; nt++)
#pragma unroll
    for (int kt = 0; kt < 5; kt++)
      Bf[nt][kt] = bfrag(W, Mp, CAT1, nt * 16 + col, Nc, kt * 32 + q * 8, Ni);
  for (int i = 0; i < 4; i++) {
    int mt = blockIdx.x * 4 + i;
    const f16* Ab = NH0 + (size_t)mt * 2560;  // 16 x 160 halves, pad cols hit zero B-rows
    h8 A[5];
#pragma unroll
    for (int kt = 0; kt < 5; kt++)
      A[kt] = *(const h8*)(Ab + col * 160 + kt * 32 + q * 8);
#pragma unroll
    for (int nt = 0; nt < 7; nt++) {
      f4 acc = {0.f, 0.f, 0.f, 0.f};
#pragma unroll
      for (int kt = 0; kt < 5; kt++) acc = MFMA(A[kt], Bf[nt][kt], acc);
      h4 o;
#pragma unroll
      for (int rr = 0; rr < 4; rr++) o[rr] = (f16)acc[rr];
      *(h4*)(XU1 + ((size_t)mt * NT1 + w * 7 + nt) * 256 + lane * 4) = o;
    }
  }
}

// ---------------- r0: sequential layer-0 recurrence, 16 WGs x 640 thr (10 waves) -----
__global__ __launch_bounds__(640, 3) void r0_kernel(
    const float* __restrict__ w1, const float* __restrict__ w2,
    const float* __restrict__ wa, const float* __restrict__ wb,
    const float* __restrict__ b1, const float* __restrict__ b2,
    const float* __restrict__ ba, const float* __restrict__ bb,
    const float* __restrict__ dtp, const f16* __restrict__ XU0,
    f16* __restrict__ NH0, f16* __restrict__ H0S, float* __restrict__ out, int c) {
  __shared__ f16 buf[2][16 * S0];
  int tid = threadIdx.x;
  int g = tid >> 6, lane = tid & 63, col = lane & 15, q = lane >> 4;
  int bt = blockIdx.x;
  int n = g * 16 + col;                      // output neuron (0..159, valid <149)
  float ts = dtp[0];
  const float* Ws[4] = {w1, w2, wa, wb};
  h8 Bf[4][5];                               // recurrent weights, resident across t-loop
#pragma unroll
  for (int mat = 0; mat < 4; mat++)
#pragma unroll
    for (int kt = 0; kt < 5; kt++)
      Bf[mat][kt] = bfrag(Ws[mat], nullptr, CAT0, n, Ni, IN_DIM + kt * 32 + q * 8, CAT0);
  float b1n = (n < Ni) ? b1[n] : 0.f, b2n = (n < Ni) ? b2[n] : 0.f;
  float ban = (n < Ni) ? ba[n] : 0.f, bbn = (n < Ni) ? bb[n] : 0.f;

  for (int idx = tid; idx < 16 * S0; idx += 640) {
    buf[0][idx] = (c == 0) ? (f16)0.f : H0S[(size_t)bt * 16 * S0 + idx];
    buf[1][idx] = (f16)0.f;
  }
  __syncthreads();

  // prefetch XU for t=0
  h4 xu[4];
#pragma unroll
  for (int mat = 0; mat < 4; mat++)
    xu[mat] = *(const h4*)(XU0 + ((size_t)bt * NT0 + mat * 10 + g) * 256 + lane * 4);

  for (int t = 0; t < TC; t++) {
    const f16* br = buf[t & 1];
    f16* bw = buf[(t + 1) & 1];
    // issue prefetch of XU(t+1) immediately; consumed next iteration
    int tn = (t + 1 < TC) ? t + 1 : t;
    size_t mtn = (size_t)tn * NBT + bt;
    h4 xun[4];
#pragma unroll
    for (int mat = 0; mat < 4; mat++)
      xun[mat] = *(const h4*)(XU0 + (mtn * NT0 + mat * 10 + g) * 256 + lane * 4);
    int mt = t * NBT + bt;
    h8 A[5];
#pragma unroll
    for (int kt = 0; kt < 5; kt++)
      A[kt] = *(const h8*)(br + col * S0 + kt * 32 + q * 8);
    f4 acc[4];
#pragma unroll
    for (int mat = 0; mat < 4; mat++) acc[mat] = (f4){0.f, 0.f, 0.f, 0.f};
#pragma unroll
    for (int kt = 0; kt < 5; kt++)
#pragma unroll
      for (int mat = 0; mat < 4; mat++)
        acc[mat] = MFMA(A[kt], Bf[mat][kt], acc[mat]);
    f16* nh = NH0 + (size_t)mt * 2560;
#pragma unroll
    for (int r = 0; r < 4; r++) {
      int m = q * 4 + r;
      float u1 = acc[0][r] + (float)xu[0][r] + b1n;
      float u2 = acc[1][r] + (float)xu[1][r] + b2n;
      float ua = acc[2][r] + (float)xu[2][r] + ban;
      float ub = acc[3][r] + (float)xu[3][r] + bbn;
      float ff1 = tanhf_(u1), ff2 = tanhf_(u2);
      float ti = sigm_(ua * ts + ub);
      float h = ff1 + (ff2 - ff1) * ti;
      f16 h16 = (f16)h;
      bw[m * S0 + n] = h16;
      nh[m * 160 + n] = h16;
      if (c == NCH - 1 && t == TC - 1 && n < Ni)
        out[YOFF + (size_t)(bt * 16 + m) * 256 + n] = h;
    }
    RAW_BAR();
#pragma unroll
    for (int mat = 0; mat < 4; mat++) xu[mat] = xun[mat];
  }
  for (int idx = tid; idx < 16 * S0; idx += 640)
    H0S[(size_t)bt * 16 * S0 + idx] = buf[0][idx];
}

// ---------------- r12: layer1 (waves 0-6) + layer2 (wave 7, half-step skew) ----------
__global__ __launch_bounds__(512, 2) void r12_kernel(
    const float* __restrict__ w1, const float* __restrict__ w2,
    const float* __restrict__ wa, const float* __restrict__ wb,
    const float* __restrict__ b1, const float* __restrict__ b2,
    const float* __restrict__ ba, const float* __restrict__ bb,
    const float* __restrict__ v1, const float* __restrict__ v2,
    const float* __restrict__ va, const float* __restrict__ vb,
    const float* __restrict__ c1, const float* __restrict__ c2,
    const float* __restrict__ ca, const float* __restrict__ cb,
    const int* __restrict__ m2, const float* __restrict__ dtp,
    const f16* __restrict__ XU1, f16* __restrict__ H12S,
    float* __restrict__ out, int c) {
  __shared__ f16 buf[2][16 * S2];  // [nh1(0..98) | h2(99..106) | pad]; B rows k>=99 are 0
  int tid = threadIdx.x;
  int w = tid >> 6, lane = tid & 63, col = lane & 15, q = lane >> 4;
  int bt = blockIdx.x;
  float ts = dtp[0];
  h8 Bf[4][4];
  float bn[4];
  if (w < 7) {
    const float* Ws[4] = {w1, w2, wa, wb};
    int n = w * 16 + col;
#pragma unroll
    for (int mat = 0; mat < 4; mat++)
#pragma unroll
      for (int kt = 0; kt < 4; kt++)
        Bf[mat][kt] = bfrag(Ws[mat], nullptr, CAT1, n, Nc, Ni + kt * 32 + q * 8, CAT1);
    bn[0] = (n < Nc) ? b1[n] : 0.f;
    bn[1] = (n < Nc) ? b2[n] : 0.f;
    bn[2] = (n < Nc) ? ba[n] : 0.f;
    bn[3] = (n < Nc) ? bb[n] : 0.f;
  } else {
    const float* Ws[4] = {v1, v2, va, vb};
#pragma unroll
    for (int mat = 0; mat < 4; mat++)
#pragma unroll
      for (int kt = 0; kt < 4; kt++)
        Bf[mat][kt] = bfrag(Ws[mat], (mat < 2) ? m2 : nullptr, CAT2, col, Nm,
                            kt * 32 + q * 8, CAT2);
    bn[0] = (col < Nm) ? c1[col] : 0.f;
    bn[1] = (col < Nm) ? c2[col] : 0.f;
    bn[2] = (col < Nm) ? ca[col] : 0.f;
    bn[3] = (col < Nm) ? cb[col] : 0.f;
  }
  for (int idx = tid; idx < 2 * 16 * S2; idx += 512)
    ((f16*)buf)[idx] = (c == 0) ? (f16)0.f : H12S[(size_t)bt * 2 * 16 * S2 + idx];
  __syncthreads();

  // prefetch XU1 for t=0 (layer-1 waves only)
  h4 xu[4];
  if (w < 7) {
#pragma unroll
    for (int mat = 0; mat < 4; mat++)
      xu[mat] = *(const h4*)(XU1 + ((size_t)bt * NT1 + mat * 7 + w) * 256 + lane * 4);
  }

  for (int t = 0; t < TC; t++) {
    f16* br = buf[t & 1];
    f16* bw = buf[(t + 1) & 1];
    h4 xun[4];
    if (w < 7) {
      int tn = (t + 1 < TC) ? t + 1 : t;
      size_t mtn = (size_t)tn * NBT + bt;
#pragma unroll
      for (int mat = 0; mat < 4; mat++)
        xun[mat] = *(const h4*)(XU1 + (mtn * NT1 + mat * 7 + w) * 256 + lane * 4);
      int n = w * 16 + col;
      h8 A[4];
#pragma unroll
      for (int kt = 0; kt < 4; kt++)
        A[kt] = *(const h8*)(br + col * S2 + kt * 32 + q * 8);
      f4 acc[4];
#pragma unroll
      for (int mat = 0; mat < 4; mat++) acc[mat] = (f4){0.f, 0.f, 0.f, 0.f};
#pragma unroll
      for (int kt = 0; kt < 4; kt++)
#pragma unroll
        for (int mat = 0; mat < 4; mat++)
          acc[mat] = MFMA(A[kt], Bf[mat][kt], acc[mat]);
#pragma unroll
      for (int r = 0; r < 4; r++) {
        int m = q * 4 + r;
        float u1 = acc[0][r] + (float)xu[0][r] + bn[0];
        float u2 = acc[1][r] + (float)xu[1][r] + bn[1];
        float ua = acc[2][r] + (float)xu[2][r] + bn[2];
        float ub = acc[3][r] + (float)xu[3][r] + bn[3];
        float ff1 = tanhf_(u1), ff2 = tanhf_(u2);
        float ti = sigm_(ua * ts + ub);
        float h = ff1 + (ff2 - ff1) * ti;
        if (n < Nc) {
          bw[m * S2 + n] = (f16)h;
          if (c == NCH - 1 && t == TC - 1)
            out[YOFF + (size_t)(bt * 16 + m) * 256 + Ni + n] = h;
        }
      }
    }
    RAW_BAR();
    if (w < 7) {
#pragma unroll
      for (int mat = 0; mat < 4; mat++) xu[mat] = xun[mat];
    }
    if (w == 7) {  // layer2(t): A = [nh1(t) | h2(t-1)] in bw; writes h2(t) into br
      int tg = c * TC + t;
      h8 A[4];
#pragma unroll
      for (int kt = 0; kt < 4; kt++)
        A[kt] = *(const h8*)(bw + col * S2 + kt * 32 + q * 8);
      f4 acc[4];
#pragma unroll
      for (int mat = 0; mat < 4; mat++) acc[mat] = (f4){0.f, 0.f, 0.f, 0.f};
#pragma unroll
      for (int kt = 0; kt < 4; kt++)
#pragma unroll
        for (int mat = 0; mat < 4; mat++)
          acc[mat] = MFMA(A[kt], Bf[mat][kt], acc[mat]);
#pragma unroll
      for (int r = 0; r < 4; r++) {
        int m = q * 4 + r;
        float u1 = acc[0][r] + bn[0];
        float u2 = acc[1][r] + bn[1];
        float ua = acc[2][r] + bn[2];
        float ub = acc[3][r] + bn[3];
        float ff1 = tanhf_(u1), ff2 = tanhf_(u2);
        float ti = sigm_(ua * ts + ub);
        float h = ff1 + (ff2 - ff1) * ti;
        if (col < Nm) {
          out[((size_t)(bt * 16 + m) * Tsz + tg) * 8 + col] = tanhf_(h);
          br[m * S2 + Nc + col] = (f16)h;
          if (c == NCH - 1 && t == TC - 1)
            out[YOFF + (size_t)(bt * 16 + m) * 256 + Ni + Nc + col] = h;
        }
      }
    }
  }
  __syncthreads();
  for (int idx = tid; idx < 2 * 16 * S2; idx += 512)
    H12S[(size_t)bt * 2 * 16 * S2 + idx] = ((f16*)buf)[idx];
}

extern "C" void kernel_launch(void* const* d_in, const int* in_sizes, int n_in,
                              void* d_out, int out_size, void* d_ws, size_t ws_size,
                              hipStream_t stream) {
  const float* w1_0 = (const float*)d_in[0];
  const float* w2_0 = (const float*)d_in[1];
  const float* wa_0 = (const float*)d_in[2];
  const float* wb_0 = (const float*)d_in[3];
  const float* b1_0 = (const float*)d_in[4];
  const float* b2_0 = (const float*)d_in[5];
  const float* ba_0 = (const float*)d_in[6];
  const float* bb_0 = (const float*)d_in[7];
  const int* m0 = (const int*)d_in[8];
  const float* w1_1 = (const float*)d_in[9];
  const float* w2_1 = (const float*)d_in[10];
  const float* wa_1 = (const float*)d_in[11];
  const float* wb_1 = (const float*)d_in[12];
  const float* b1_1 = (const float*)d_in[13];
  const float* b2_1 = (const float*)d_in[14];
  const float* ba_1 = (const float*)d_in[15];
  const float* bb_1 = (const float*)d_in[16];
  const int* m1 = (const int*)d_in[17];
  const float* w1_2 = (const float*)d_in[18];
  const float* w2_2 = (const float*)d_in[19];
  const float* wa_2 = (const float*)d_in[20];
  const float* wb_2 = (const float*)d_in[21];
  const float* c1 = (const float*)d_in[22];
  const float* c2 = (const float*)d_in[23];
  const float* ca = (const float*)d_in[24];
  const float* cb = (const float*)d_in[25];
  const int* m2 = (const int*)d_in[26];
  const float* x = (const float*)d_in[27];
  const float* dt = (const float*)d_in[28];
  float* out = (float*)d_out;

  f16* XU0 = (f16*)d_ws;
  f16* NH0 = XU0 + XU0_HALVES;
  f16* XU1 = NH0 + NH0_HALVES;
  f16* H0S = XU1 + XU1_HALVES;
  f16* H12S = H0S + H0S_HALVES;

  for (int c = 0; c < NCH; c++) {
    x0_kernel<<<512, 256, 0, stream>>>(w1_0, w2_0, wa_0, wb_0, m0, x, XU0, c);
    r0_kernel<<<16, 640, 0, stream>>>(w1_0, w2_0, wa_0, wb_0, b1_0, b2_0, ba_0, bb_0,
                                      dt, XU0, NH0, H0S, out, c);
    x1_kernel<<<512, 256, 0, stream>>>(w1_1, w2_1, wa_1, wb_1, m1, NH0, XU1);
    r12_kernel<<<16, 512, 0, stream>>>(w1_1, w2_1, wa_1, wb_1, b1_1, b2_1, ba_1, bb_1,
                                       w1_2, w2_2, wa_2, wb_2, c1, c2, ca, cb, m2, dt,
                                       XU1, H12S, out, c);
  }
}

// Round 3
// 1486.379 us; speedup vs baseline: 1.9524x; 1.8444x over previous
//
#include <hip/hip_runtime.h>
#include <cmath>

// CfC-NCP RNN, phase-decomposed:
//   pack (once/call): weight fragments -> h8 in ws.
//   per chunk c (TC=128 steps): x0 (parallel GEMM x->XU0), r0 (recurrent layer0,
//   weights resident in VGPRs, 16 WGs = 16 batch tiles), x1 (parallel GEMM nh0->XU1),
//   r12 (recurrent layer1 on waves 0-6 + layer2 on wave 7, half-step skewed).
// fp16 MFMA inputs, fp32 accum. Workspace ~83 MB.
// R1: XU prefetch + raw lgkmcnt-only barrier.
// R2: (a) pre-packed weight fragments (bfrag's masked scalar loads ran per-thread in
//     EVERY kernel: ~340MB scattered traffic per x0 launch); (b) MFMA/epilogue
//     interleave in r0/r12 so matrix + VALU pipes overlap instead of phase-serializing.

typedef _Float16 f16;
typedef f16 h4 __attribute__((ext_vector_type(4)));
typedef f16 h8 __attribute__((ext_vector_type(8)));
typedef float f4 __attribute__((ext_vector_type(4)));

#define MFMA(a, b, c) __builtin_amdgcn_mfma_f32_16x16x32_f16(a, b, c, 0, 0, 0)
// LDS-only barrier: waves drain their own LDS ops (lgkmcnt) then sync; global ops
// (XU prefetch loads, NH0/y stores) intentionally left in flight.
#define RAW_BAR() asm volatile("s_waitcnt lgkmcnt(0)\n\ts_barrier" ::: "memory")

constexpr int IN_DIM = 128, Ni = 149, Nc = 99, Nm = 8;
constexpr int CAT0 = 277, CAT1 = 248, CAT2 = 107;
constexpr int Bsz = 256, Tsz = 512;
constexpr int TC = 128, NCH = 4, NBT = 16;
constexpr int NT0 = 40, NT1 = 28;        // fragment tile-columns (4 mats x n-tiles)
constexpr int S0 = 168, S2 = 136;        // LDS row strides (halves), bank-conflict pad
constexpr size_t XU0_HALVES = (size_t)TC * NBT * NT0 * 256;  // 20,971,520
constexpr size_t NH0_HALVES = (size_t)TC * NBT * 16 * 160;   //  5,242,880
constexpr size_t XU1_HALVES = (size_t)TC * NBT * NT1 * 256;  // 14,680,064
constexpr size_t H0S_HALVES = (size_t)NBT * 16 * S0;
constexpr size_t H12S_HALVES = (size_t)NBT * 2 * 16 * S2;
constexpr size_t YOFF = (size_t)Bsz * Tsz * 8;  // h_out offset in d_out

// packed-fragment segment offsets (h8 units)
constexpr int OFF_X0 = 0;          // [w4][nt10][kt4][lane64]
constexpr int OFF_R0 = 10240;      // [g10][mat4][kt5][lane64]
constexpr int OFF_X1 = 23040;      // [w4][nt7][kt5][lane64]
constexpr int OFF_R12A = 32000;    // [w7][mat4][kt4][lane64]
constexpr int OFF_R12B = 39168;    // [mat4][kt4][lane64]
constexpr int NFRAG = 40192;
constexpr size_t PK_HALVES = (size_t)NFRAG * 8;

__device__ inline float rcpf_(float x) { return __builtin_amdgcn_rcpf(x); }
__device__ inline float tanhf_(float x) {
  float e = __expf(-2.f * fabsf(x));          // in (0,1], no overflow
  float t = (1.f - e) * rcpf_(1.f + e);
  return x < 0.f ? -t : t;
}
__device__ inline float sigm_(float z) { return rcpf_(1.f + __expf(-z)); }

// B-fragment builder: lane holds B[k = k0..k0+7][n], n = per-lane row of W (out = xh @ W^T).
__device__ inline h8 bfrag(const float* W, const int* M, int ld, int n, int nmax,
                           int k0, int kmax) {
  h8 r;
#pragma unroll
  for (int j = 0; j < 8; j++) {
    int k = k0 + j;
    float v = 0.f;
    if (n < nmax && k < kmax) {
      v = W[(size_t)n * ld + k];
      if (M) v *= (float)M[(size_t)n * ld + k];
    }
    r[j] = (f16)v;
  }
  return r;
}

// ---------------- pack: build all h8 weight fragments once per call ------------------
__global__ __launch_bounds__(256) void pack_kernel(
    const float* __restrict__ w1_0, const float* __restrict__ w2_0,
    const float* __restrict__ wa_0, const float* __restrict__ wb_0,
    const int* __restrict__ m0,
    const float* __restrict__ w1_1, const float* __restrict__ w2_1,
    const float* __restrict__ wa_1, const float* __restrict__ wb_1,
    const int* __restrict__ m1,
    const float* __restrict__ w1_2, const float* __restrict__ w2_2,
    const float* __restrict__ wa_2, const float* __restrict__ wb_2,
    const int* __restrict__ m2, f16* __restrict__ PK) {
  int idx = blockIdx.x * 256 + threadIdx.x;
  if (idx >= NFRAG) return;
  int lane = idx & 63, col = lane & 15, q = lane >> 4;
  const float* W;
  const int* M = nullptr;
  int ld, n, nmax, k0, kmax;
  if (idx < OFF_R0) {  // x0
    int i = idx;
    int w = i / 2560, nt = (i / 256) % 10, kt = (i / 64) % 4;
    const float* Ws[4] = {w1_0, w2_0, wa_0, wb_0};
    W = Ws[w]; M = (w < 2) ? m0 : nullptr;
    ld = CAT0; n = nt * 16 + col; nmax = Ni; k0 = kt * 32 + q * 8; kmax = IN_DIM;
  } else if (idx < OFF_X1) {  // r0
    int i = idx - OFF_R0;
    int g = i / 1280, mat = (i / 320) % 4, kt = (i / 64) % 5;
    const float* Ws[4] = {w1_0, w2_0, wa_0, wb_0};
    W = Ws[mat];
    ld = CAT0; n = g * 16 + col; nmax = Ni; k0 = IN_DIM + kt * 32 + q * 8; kmax = CAT0;
  } else if (idx < OFF_R12A) {  // x1
    int i = idx - OFF_X1;
    int w = i / 2240, nt = (i / 320) % 7, kt = (i / 64) % 5;
    const float* Ws[4] = {w1_1, w2_1, wa_1, wb_1};
    W = Ws[w]; M = (w < 2) ? m1 : nullptr;
    ld = CAT1; n = nt * 16 + col; nmax = Nc; k0 = kt * 32 + q * 8; kmax = Ni;
  } else if (idx < OFF_R12B) {  // r12 layer1
    int i = idx - OFF_R12A;
    int w = i / 1024, mat = (i / 256) % 4, kt = (i / 64) % 4;
    const float* Ws[4] = {w1_1, w2_1, wa_1, wb_1};
    W = Ws[mat];
    ld = CAT1; n = w * 16 + col; nmax = Nc; k0 = Ni + kt * 32 + q * 8; kmax = CAT1;
  } else {  // r12 layer2
    int i = idx - OFF_R12B;
    int mat = i / 256, kt = (i / 64) % 4;
    const float* Ws[4] = {w1_2, w2_2, wa_2, wb_2};
    W = Ws[mat]; M = (mat < 2) ? m2 : nullptr;
    ld = CAT2; n = col; nmax = Nm; k0 = kt * 32 + q * 8; kmax = CAT2;
  }
  ((h8*)PK)[idx] = bfrag(W, M, ld, n, nmax, k0, kmax);
}

// ---------------- x0: XU0[mt, mat*10+nt, frag] = x(t) @ Wx0^T (masked w1,w2) ---------
__global__ __launch_bounds__(256, 2) void x0_kernel(
    const h8* __restrict__ pk, const float* __restrict__ x,
    f16* __restrict__ XU0, int c) {
  __shared__ f16 stg[16 * 136];
  int tid = threadIdx.x;
  int w = tid >> 6, lane = tid & 63, col = lane & 15, q = lane >> 4;
  h8 Bf[10][4];
#pragma unroll
  for (int nt = 0; nt < 10; nt++)
#pragma unroll
    for (int kt = 0; kt < 4; kt++)
      Bf[nt][kt] = pk[OFF_X0 + ((w * 10 + nt) * 4 + kt) * 64 + lane];

  int sr = tid >> 4, sc = (tid & 15) * 8;
  for (int i = 0; i < 4; i++) {
    int mt = blockIdx.x * 4 + i;          // 0..2047 = t_local*16 + bt
    int tl = mt >> 4, bt = mt & 15;
    int tg = c * TC + tl;
    const float* xp = x + ((size_t)(bt * 16 + sr) * Tsz + tg) * IN_DIM + sc;
    h8 hv;
#pragma unroll
    for (int j = 0; j < 8; j++) hv[j] = (f16)xp[j];
    *(h8*)(stg + sr * 136 + sc) = hv;
    __syncthreads();
    h8 A[4];
#pragma unroll
    for (int kt = 0; kt < 4; kt++)
      A[kt] = *(const h8*)(stg + col * 136 + kt * 32 + q * 8);
#pragma unroll
    for (int nt = 0; nt < 10; nt++) {
      f4 acc = {0.f, 0.f, 0.f, 0.f};
#pragma unroll
      for (int kt = 0; kt < 4; kt++) acc = MFMA(A[kt], Bf[nt][kt], acc);
      h4 o;
#pragma unroll
      for (int rr = 0; rr < 4; rr++) o[rr] = (f16)acc[rr];
      *(h4*)(XU0 + ((size_t)mt * NT0 + w * 10 + nt) * 256 + lane * 4) = o;
    }
    __syncthreads();
  }
}

// ---------------- x1: XU1[mt, mat*7+nt, frag] = nh0(t) @ Wx1^T (masked w1,w2) --------
__global__ __launch_bounds__(256, 2) void x1_kernel(
    const h8* __restrict__ pk, const f16* __restrict__ NH0, f16* __restrict__ XU1) {
  int tid = threadIdx.x;
  int w = tid >> 6, lane = tid & 63, col = lane & 15, q = lane >> 4;
  h8 Bf[7][5];
#pragma unroll
  for (int nt = 0; nt < 7; nt++)
#pragma unroll
    for (int kt = 0; kt < 5; kt++)
      Bf[nt][kt] = pk[OFF_X1 + ((w * 7 + nt) * 5 + kt) * 64 + lane];
  for (int i = 0; i < 4; i++) {
    int mt = blockIdx.x * 4 + i;
    const f16* Ab = NH0 + (size_t)mt * 2560;  // 16 x 160 halves, pad cols hit zero B-rows
    h8 A[5];
#pragma unroll
    for (int kt = 0; kt < 5; kt++)
      A[kt] = *(const h8*)(Ab + col * 160 + kt * 32 + q * 8);
#pragma unroll
    for (int nt = 0; nt < 7; nt++) {
      f4 acc = {0.f, 0.f, 0.f, 0.f};
#pragma unroll
      for (int kt = 0; kt < 5; kt++) acc = MFMA(A[kt], Bf[nt][kt], acc);
      h4 o;
#pragma unroll
      for (int rr = 0; rr < 4; rr++) o[rr] = (f16)acc[rr];
      *(h4*)(XU1 + ((size_t)mt * NT1 + w * 7 + nt) * 256 + lane * 4) = o;
    }
  }
}

// ---------------- r0: sequential layer-0 recurrence, 16 WGs x 640 thr (10 waves) -----
__global__ __launch_bounds__(640, 3) void r0_kernel(
    const h8* __restrict__ pk,
    const float* __restrict__ b1, const float* __restrict__ b2,
    const float* __restrict__ ba, const float* __restrict__ bb,
    const float* __restrict__ dtp, const f16* __restrict__ XU0,
    f16* __restrict__ NH0, f16* __restrict__ H0S, float* __restrict__ out, int c) {
  __shared__ f16 buf[2][16 * S0];
  int tid = threadIdx.x;
  int g = tid >> 6, lane = tid & 63, col = lane & 15, q = lane >> 4;
  int bt = blockIdx.x;
  int n = g * 16 + col;                      // output neuron (0..159, valid <149)
  float ts = dtp[0];
  h8 Bf[4][5];                               // recurrent weights, resident across t-loop
#pragma unroll
  for (int mat = 0; mat < 4; mat++)
#pragma unroll
    for (int kt = 0; kt < 5; kt++)
      Bf[mat][kt] = pk[OFF_R0 + ((g * 4 + mat) * 5 + kt) * 64 + lane];
  float b1n = (n < Ni) ? b1[n] : 0.f, b2n = (n < Ni) ? b2[n] : 0.f;
  float ban = (n < Ni) ? ba[n] : 0.f, bbn = (n < Ni) ? bb[n] : 0.f;

  for (int idx = tid; idx < 16 * S0; idx += 640) {
    buf[0][idx] = (c == 0) ? (f16)0.f : H0S[(size_t)bt * 16 * S0 + idx];
    buf[1][idx] = (f16)0.f;
  }
  __syncthreads();

  // prefetch XU for t=0
  h4 xu[4];
#pragma unroll
  for (int mat = 0; mat < 4; mat++)
    xu[mat] = *(const h4*)(XU0 + ((size_t)bt * NT0 + mat * 10 + g) * 256 + lane * 4);

  for (int t = 0; t < TC; t++) {
    const f16* br = buf[t & 1];
    f16* bw = buf[(t + 1) & 1];
    // issue prefetch of XU(t+1) immediately; consumed next iteration
    int tn = (t + 1 < TC) ? t + 1 : t;
    size_t mtn = (size_t)tn * NBT + bt;
    h4 xun[4];
#pragma unroll
    for (int mat = 0; mat < 4; mat++)
      xun[mat] = *(const h4*)(XU0 + (mtn * NT0 + mat * 10 + g) * 256 + lane * 4);
    int mt = t * NBT + bt;
    h8 A[5];
#pragma unroll
    for (int kt = 0; kt < 5; kt++)
      A[kt] = *(const h8*)(br + col * S0 + kt * 32 + q * 8);
    // mats 0,1 first ...
    f4 acc0 = {0.f, 0.f, 0.f, 0.f}, acc1 = acc0, acc2 = acc0, acc3 = acc0;
#pragma unroll
    for (int kt = 0; kt < 5; kt++) {
      acc0 = MFMA(A[kt], Bf[0][kt], acc0);
      acc1 = MFMA(A[kt], Bf[1][kt], acc1);
    }
    // ... tanh part overlaps other waves' MFMAs ...
    float ff1[4], ff2[4];
#pragma unroll
    for (int r = 0; r < 4; r++) {
      float u1 = acc0[r] + (float)xu[0][r] + b1n;
      float u2 = acc1[r] + (float)xu[1][r] + b2n;
      ff1[r] = tanhf_(u1);
      ff2[r] = tanhf_(u2);
    }
    // ... mats 2,3 ...
#pragma unroll
    for (int kt = 0; kt < 5; kt++) {
      acc2 = MFMA(A[kt], Bf[2][kt], acc2);
      acc3 = MFMA(A[kt], Bf[3][kt], acc3);
    }
    f16* nh = NH0 + (size_t)mt * 2560;
#pragma unroll
    for (int r = 0; r < 4; r++) {
      int m = q * 4 + r;
      float ua = acc2[r] + (float)xu[2][r] + ban;
      float ub = acc3[r] + (float)xu[3][r] + bbn;
      float ti = sigm_(ua * ts + ub);
      float h = ff1[r] + (ff2[r] - ff1[r]) * ti;
      f16 h16 = (f16)h;
      bw[m * S0 + n] = h16;
      nh[m * 160 + n] = h16;
      if (c == NCH - 1 && t == TC - 1 && n < Ni)
        out[YOFF + (size_t)(bt * 16 + m) * 256 + n] = h;
    }
    RAW_BAR();
#pragma unroll
    for (int mat = 0; mat < 4; mat++) xu[mat] = xun[mat];
  }
  for (int idx = tid; idx < 16 * S0; idx += 640)
    H0S[(size_t)bt * 16 * S0 + idx] = buf[0][idx];
}

// ---------------- r12: layer1 (waves 0-6) + layer2 (wave 7, half-step skew) ----------
__global__ __launch_bounds__(512, 2) void r12_kernel(
    const h8* __restrict__ pk,
    const float* __restrict__ b1, const float* __restrict__ b2,
    const float* __restrict__ ba, const float* __restrict__ bb,
    const float* __restrict__ c1, const float* __restrict__ c2,
    const float* __restrict__ ca, const float* __restrict__ cb,
    const float* __restrict__ dtp, const f16* __restrict__ XU1,
    f16* __restrict__ H12S, float* __restrict__ out, int c) {
  __shared__ f16 buf[2][16 * S2];  // [nh1(0..98) | h2(99..106) | pad]; B rows k>=99 are 0
  int tid = threadIdx.x;
  int w = tid >> 6, lane = tid & 63, col = lane & 15, q = lane >> 4;
  int bt = blockIdx.x;
  float ts = dtp[0];
  h8 Bf[4][4];
  float bn[4];
  if (w < 7) {
    int n = w * 16 + col;
#pragma unroll
    for (int mat = 0; mat < 4; mat++)
#pragma unroll
      for (int kt = 0; kt < 4; kt++)
        Bf[mat][kt] = pk[OFF_R12A + ((w * 4 + mat) * 4 + kt) * 64 + lane];
    bn[0] = (n < Nc) ? b1[n] : 0.f;
    bn[1] = (n < Nc) ? b2[n] : 0.f;
    bn[2] = (n < Nc) ? ba[n] : 0.f;
    bn[3] = (n < Nc) ? bb[n] : 0.f;
  } else {
#pragma unroll
    for (int mat = 0; mat < 4; mat++)
#pragma unroll
      for (int kt = 0; kt < 4; kt++)
        Bf[mat][kt] = pk[OFF_R12B + (mat * 4 + kt) * 64 + lane];
    bn[0] = (col < Nm) ? c1[col] : 0.f;
    bn[1] = (col < Nm) ? c2[col] : 0.f;
    bn[2] = (col < Nm) ? ca[col] : 0.f;
    bn[3] = (col < Nm) ? cb[col] : 0.f;
  }
  for (int idx = tid; idx < 2 * 16 * S2; idx += 512)
    ((f16*)buf)[idx] = (c == 0) ? (f16)0.f : H12S[(size_t)bt * 2 * 16 * S2 + idx];
  __syncthreads();

  // prefetch XU1 for t=0 (layer-1 waves only)
  h4 xu[4];
  if (w < 7) {
#pragma unroll
    for (int mat = 0; mat < 4; mat++)
      xu[mat] = *(const h4*)(XU1 + ((size_t)bt * NT1 + mat * 7 + w) * 256 + lane * 4);
  }

  for (int t = 0; t < TC; t++) {
    f16* br = buf[t & 1];
    f16* bw = buf[(t + 1) & 1];
    h4 xun[4];
    if (w < 7) {
      int tn = (t + 1 < TC) ? t + 1 : t;
      size_t mtn = (size_t)tn * NBT + bt;
#pragma unroll
      for (int mat = 0; mat < 4; mat++)
        xun[mat] = *(const h4*)(XU1 + (mtn * NT1 + mat * 7 + w) * 256 + lane * 4);
      int n = w * 16 + col;
      h8 A[4];
#pragma unroll
      for (int kt = 0; kt < 4; kt++)
        A[kt] = *(const h8*)(br + col * S2 + kt * 32 + q * 8);
      f4 acc0 = {0.f, 0.f, 0.f, 0.f}, acc1 = acc0, acc2 = acc0, acc3 = acc0;
#pragma unroll
      for (int kt = 0; kt < 4; kt++) {
        acc0 = MFMA(A[kt], Bf[0][kt], acc0);
        acc1 = MFMA(A[kt], Bf[1][kt], acc1);
      }
      float ff1[4], ff2[4];
#pragma unroll
      for (int r = 0; r < 4; r++) {
        float u1 = acc0[r] + (float)xu[0][r] + bn[0];
        float u2 = acc1[r] + (float)xu[1][r] + bn[1];
        ff1[r] = tanhf_(u1);
        ff2[r] = tanhf_(u2);
      }
#pragma unroll
      for (int kt = 0; kt < 4; kt++) {
        acc2 = MFMA(A[kt], Bf[2][kt], acc2);
        acc3 = MFMA(A[kt], Bf[3][kt], acc3);
      }
#pragma unroll
      for (int r = 0; r < 4; r++) {
        int m = q * 4 + r;
        float ua = acc2[r] + (float)xu[2][r] + bn[2];
        float ub = acc3[r] + (float)xu[3][r] + bn[3];
        float ti = sigm_(ua * ts + ub);
        float h = ff1[r] + (ff2[r] - ff1[r]) * ti;
        if (n < Nc) {
          bw[m * S2 + n] = (f16)h;
          if (c == NCH - 1 && t == TC - 1)
            out[YOFF + (size_t)(bt * 16 + m) * 256 + Ni + n] = h;
        }
      }
    }
    RAW_BAR();
    if (w < 7) {
#pragma unroll
      for (int mat = 0; mat < 4; mat++) xu[mat] = xun[mat];
    }
    if (w == 7) {  // layer2(t): A = [nh1(t) | h2(t-1)] in bw; writes h2(t) into br
      int tg = c * TC + t;
      h8 A[4];
#pragma unroll
      for (int kt = 0; kt < 4; kt++)
        A[kt] = *(const h8*)(bw + col * S2 + kt * 32 + q * 8);
      f4 acc0 = {0.f, 0.f, 0.f, 0.f}, acc1 = acc0, acc2 = acc0, acc3 = acc0;
#pragma unroll
      for (int kt = 0; kt < 4; kt++) {
        acc0 = MFMA(A[kt], Bf[0][kt], acc0);
        acc1 = MFMA(A[kt], Bf[1][kt], acc1);
        acc2 = MFMA(A[kt], Bf[2][kt], acc2);
        acc3 = MFMA(A[kt], Bf[3][kt], acc3);
      }
#pragma unroll
      for (int r = 0; r < 4; r++) {
        int m = q * 4 + r;
        float u1 = acc0[r] + bn[0];
        float u2 = acc1[r] + bn[1];
        float ua = acc2[r] + bn[2];
        float ub = acc3[r] + bn[3];
        float ff1 = tanhf_(u1), ff2 = tanhf_(u2);
        float ti = sigm_(ua * ts + ub);
        float h = ff1 + (ff2 - ff1) * ti;
        if (col < Nm) {
          out[((size_t)(bt * 16 + m) * Tsz + tg) * 8 + col] = tanhf_(h);
          br[m * S2 + Nc + col] = (f16)h;
          if (c == NCH - 1 && t == TC - 1)
            out[YOFF + (size_t)(bt * 16 + m) * 256 + Ni + Nc + col] = h;
        }
      }
    }
  }
  __syncthreads();
  for (int idx = tid; idx < 2 * 16 * S2; idx += 512)
    H12S[(size_t)bt * 2 * 16 * S2 + idx] = ((f16*)buf)[idx];
}

extern "C" void kernel_launch(void* const* d_in, const int* in_sizes, int n_in,
                              void* d_out, int out_size, void* d_ws, size_t ws_size,
                              hipStream_t stream) {
  const float* w1_0 = (const float*)d_in[0];
  const float* w2_0 = (const float*)d_in[1];
  const float* wa_0 = (const float*)d_in[2];
  const float* wb_0 = (const float*)d_in[3];
  const float* b1_0 = (const float*)d_in[4];
  const float* b2_0 = (const float*)d_in[5];
  const float* ba_0 = (const float*)d_in[6];
  const float* bb_0 = (const float*)d_in[7];
  const int* m0 = (const int*)d_in[8];
  const float* w1_1 = (const float*)d_in[9];
  const float* w2_1 = (const float*)d_in[10];
  const float* wa_1 = (const float*)d_in[11];
  const float* wb_1 = (const float*)d_in[12];
  const float* b1_1 = (const float*)d_in[13];
  const float* b2_1 = (const float*)d_in[14];
  const float* ba_1 = (const float*)d_in[15];
  const float* bb_1 = (const float*)d_in[16];
  const int* m1 = (const int*)d_in[17];
  const float* w1_2 = (const float*)d_in[18];
  const float* w2_2 = (const float*)d_in[19];
  const float* wa_2 = (const float*)d_in[20];
  const float* wb_2 = (const float*)d_in[21];
  const float* c1 = (const float*)d_in[22];
  const float* c2 = (const float*)d_in[23];
  const float* ca = (const float*)d_in[24];
  const float* cb = (const float*)d_in[25];
  const int* m2 = (const int*)d_in[26];
  const float* x = (const float*)d_in[27];
  const float* dt = (const float*)d_in[28];
  float* out = (float*)d_out;

  f16* XU0 = (f16*)d_ws;
  f16* NH0 = XU0 + XU0_HALVES;
  f16* XU1 = NH0 + NH0_HALVES;
  f16* H0S = XU1 + XU1_HALVES;
  f16* H12S = H0S + H0S_HALVES;
  f16* PK = H12S + H12S_HALVES;
  const h8* pk = (const h8*)PK;

  pack_kernel<<<(NFRAG + 255) / 256, 256, 0, stream>>>(
      w1_0, w2_0, wa_0, wb_0, m0, w1_1, w2_1, wa_1, wb_1, m1,
      w1_2, w2_2, wa_2, wb_2, m2, PK);

  for (int c = 0; c < NCH; c++) {
    x0_kernel<<<512, 256, 0, stream>>>(pk, x, XU0, c);
    r0_kernel<<<16, 640, 0, stream>>>(pk, b1_0, b2_0, ba_0, bb_0, dt, XU0, NH0, H0S,
                                      out, c);
    x1_kernel<<<512, 256, 0, stream>>>(pk, NH0, XU1);
    r12_kernel<<<16, 512, 0, stream>>>(pk, b1_1, b2_1, ba_1, bb_1, c1, c2, ca, cb, dt,
                                       XU1, H12S, out, c);
  }
}

// Round 4
// 1090.162 us; speedup vs baseline: 2.6620x; 1.3634x over previous
//
#include <hip/hip_runtime.h>
#include <cmath>

// CfC-NCP RNN, phase-decomposed + chunk-pipelined:
//   pack (once): weight fragments -> h8 in ws.
//   X(-1): x0(0).  Then c=0..4: R(c) = [r0(c) on WGs 0-15 | r12(c-1) on WGs 16-31],
//   and for c<4: X(c) = [x1(c) on WGs 0-511 | x0(c+1) on WGs 512-1023].
// r12(c-1) is data-independent of r0(c) (reads XU1(c-1)); x0(c+1) independent of
// x1(c). Stream order provides all hazard edges (XU0/XU1/NH0 single-buffered).
// fp16 MFMA inputs, fp32 accum. Workspace ~84 MB.
// R1: XU prefetch + raw lgkmcnt-only barrier. R2: packed weights + MFMA/epilogue
// interleave. R3: WG-split pipelining (r0||r12, x1||x0) — phases overlap on
// disjoint CUs instead of serializing across launches.

typedef _Float16 f16;
typedef f16 h4 __attribute__((ext_vector_type(4)));
typedef f16 h8 __attribute__((ext_vector_type(8)));
typedef float f4 __attribute__((ext_vector_type(4)));

#define MFMA(a, b, c) __builtin_amdgcn_mfma_f32_16x16x32_f16(a, b, c, 0, 0, 0)
// LDS-only barrier: waves drain their own LDS ops (lgkmcnt) then sync; global ops
// (XU prefetch loads, NH0/y stores) intentionally left in flight.
#define RAW_BAR() asm volatile("s_waitcnt lgkmcnt(0)\n\ts_barrier" ::: "memory")

constexpr int IN_DIM = 128, Ni = 149, Nc = 99, Nm = 8;
constexpr int CAT0 = 277, CAT1 = 248, CAT2 = 107;
constexpr int Bsz = 256, Tsz = 512;
constexpr int TC = 128, NCH = 4, NBT = 16;
constexpr int NT0 = 40, NT1 = 28;        // fragment tile-columns (4 mats x n-tiles)
constexpr int S0 = 168, S2 = 136;        // LDS row strides (halves), bank-conflict pad
constexpr size_t XU0_HALVES = (size_t)TC * NBT * NT0 * 256;  // 20,971,520
constexpr size_t NH0_HALVES = (size_t)TC * NBT * 16 * 160;   //  5,242,880
constexpr size_t XU1_HALVES = (size_t)TC * NBT * NT1 * 256;  // 14,680,064
constexpr size_t H0S_HALVES = (size_t)NBT * 16 * S0;
constexpr size_t H12S_HALVES = (size_t)NBT * 2 * 16 * S2;
constexpr size_t YOFF = (size_t)Bsz * Tsz * 8;  // h_out offset in d_out

// packed-fragment segment offsets (h8 units)
constexpr int OFF_X0 = 0;          // [w4][nt10][kt4][lane64]
constexpr int OFF_R0 = 10240;      // [g10][mat4][kt5][lane64]
constexpr int OFF_X1 = 23040;      // [w4][nt7][kt5][lane64]
constexpr int OFF_R12A = 32000;    // [w7][mat4][kt4][lane64]
constexpr int OFF_R12B = 39168;    // [mat4][kt4][lane64]
constexpr int NFRAG = 40192;

__device__ inline float rcpf_(float x) { return __builtin_amdgcn_rcpf(x); }
__device__ inline float tanhf_(float x) {
  float e = __expf(-2.f * fabsf(x));          // in (0,1], no overflow
  float t = (1.f - e) * rcpf_(1.f + e);
  return x < 0.f ? -t : t;
}
__device__ inline float sigm_(float z) { return rcpf_(1.f + __expf(-z)); }

// B-fragment builder: lane holds B[k = k0..k0+7][n], n = per-lane row of W (out = xh @ W^T).
__device__ inline h8 bfrag(const float* W, const int* M, int ld, int n, int nmax,
                           int k0, int kmax) {
  h8 r;
#pragma unroll
  for (int j = 0; j < 8; j++) {
    int k = k0 + j;
    float v = 0.f;
    if (n < nmax && k < kmax) {
      v = W[(size_t)n * ld + k];
      if (M) v *= (float)M[(size_t)n * ld + k];
    }
    r[j] = (f16)v;
  }
  return r;
}

// ---------------- pack: build all h8 weight fragments once per call ------------------
__global__ __launch_bounds__(256) void pack_kernel(
    const float* __restrict__ w1_0, const float* __restrict__ w2_0,
    const float* __restrict__ wa_0, const float* __restrict__ wb_0,
    const int* __restrict__ m0,
    const float* __restrict__ w1_1, const float* __restrict__ w2_1,
    const float* __restrict__ wa_1, const float* __restrict__ wb_1,
    const int* __restrict__ m1,
    const float* __restrict__ w1_2, const float* __restrict__ w2_2,
    const float* __restrict__ wa_2, const float* __restrict__ wb_2,
    const int* __restrict__ m2, f16* __restrict__ PK) {
  int idx = blockIdx.x * 256 + threadIdx.x;
  if (idx >= NFRAG) return;
  int lane = idx & 63, col = lane & 15, q = lane >> 4;
  const float* W;
  const int* M = nullptr;
  int ld, n, nmax, k0, kmax;
  if (idx < OFF_R0) {  // x0
    int i = idx;
    int w = i / 2560, nt = (i / 256) % 10, kt = (i / 64) % 4;
    const float* Ws[4] = {w1_0, w2_0, wa_0, wb_0};
    W = Ws[w]; M = (w < 2) ? m0 : nullptr;
    ld = CAT0; n = nt * 16 + col; nmax = Ni; k0 = kt * 32 + q * 8; kmax = IN_DIM;
  } else if (idx < OFF_X1) {  // r0
    int i = idx - OFF_R0;
    int g = i / 1280, mat = (i / 320) % 4, kt = (i / 64) % 5;
    const float* Ws[4] = {w1_0, w2_0, wa_0, wb_0};
    W = Ws[mat];
    ld = CAT0; n = g * 16 + col; nmax = Ni; k0 = IN_DIM + kt * 32 + q * 8; kmax = CAT0;
  } else if (idx < OFF_R12A) {  // x1
    int i = idx - OFF_X1;
    int w = i / 2240, nt = (i / 320) % 7, kt = (i / 64) % 5;
    const float* Ws[4] = {w1_1, w2_1, wa_1, wb_1};
    W = Ws[w]; M = (w < 2) ? m1 : nullptr;
    ld = CAT1; n = nt * 16 + col; nmax = Nc; k0 = kt * 32 + q * 8; kmax = Ni;
  } else if (idx < OFF_R12B) {  // r12 layer1
    int i = idx - OFF_R12A;
    int w = i / 1024, mat = (i / 256) % 4, kt = (i / 64) % 4;
    const float* Ws[4] = {w1_1, w2_1, wa_1, wb_1};
    W = Ws[mat];
    ld = CAT1; n = w * 16 + col; nmax = Nc; k0 = Ni + kt * 32 + q * 8; kmax = CAT1;
  } else {  // r12 layer2
    int i = idx - OFF_R12B;
    int mat = i / 256, kt = (i / 64) % 4;
    const float* Ws[4] = {w1_2, w2_2, wa_2, wb_2};
    W = Ws[mat]; M = (mat < 2) ? m2 : nullptr;
    ld = CAT2; n = col; nmax = Nm; k0 = kt * 32 + q * 8; kmax = CAT2;
  }
  ((h8*)PK)[idx] = bfrag(W, M, ld, n, nmax, k0, kmax);
}

// ---------------- X: [x1(c) | x0(c+1)] on disjoint WG ranges -------------------------
// x0: XU0[mt, mat*10+nt, frag] = x(t) @ Wx0^T.  x1: XU1[...] = nh0(t) @ Wx1^T.
__global__ __launch_bounds__(256, 2) void X_kernel(
    const h8* __restrict__ pk, const float* __restrict__ x,
    const f16* __restrict__ NH0, f16* __restrict__ XU0, f16* __restrict__ XU1,
    int c) {
  __shared__ f16 stg[16 * 136];
  int tid = threadIdx.x;
  int w = tid >> 6, lane = tid & 63, col = lane & 15, q = lane >> 4;
  int wg = blockIdx.x;
  if (wg < 512) {  // ---- x1 for chunk c ----
    if (c < 0) return;
    h8 Bf[7][5];
#pragma unroll
    for (int nt = 0; nt < 7; nt++)
#pragma unroll
      for (int kt = 0; kt < 5; kt++)
        Bf[nt][kt] = pk[OFF_X1 + ((w * 7 + nt) * 5 + kt) * 64 + lane];
    for (int i = 0; i < 4; i++) {
      int mt = wg * 4 + i;
      const f16* Ab = NH0 + (size_t)mt * 2560;  // 16x160 halves; pad cols hit zero B-rows
      h8 A[5];
#pragma unroll
      for (int kt = 0; kt < 5; kt++)
        A[kt] = *(const h8*)(Ab + col * 160 + kt * 32 + q * 8);
#pragma unroll
      for (int nt = 0; nt < 7; nt++) {
        f4 acc = {0.f, 0.f, 0.f, 0.f};
#pragma unroll
        for (int kt = 0; kt < 5; kt++) acc = MFMA(A[kt], Bf[nt][kt], acc);
        h4 o;
#pragma unroll
        for (int rr = 0; rr < 4; rr++) o[rr] = (f16)acc[rr];
        *(h4*)(XU1 + ((size_t)mt * NT1 + w * 7 + nt) * 256 + lane * 4) = o;
      }
    }
  } else {  // ---- x0 for chunk c+1 ----
    int cn = c + 1;
    if (cn >= NCH) return;
    int bx = wg - 512;
    h8 Bf[10][4];
#pragma unroll
    for (int nt = 0; nt < 10; nt++)
#pragma unroll
      for (int kt = 0; kt < 4; kt++)
        Bf[nt][kt] = pk[OFF_X0 + ((w * 10 + nt) * 4 + kt) * 64 + lane];
    int sr = tid >> 4, sc = (tid & 15) * 8;
    for (int i = 0; i < 4; i++) {
      int mt = bx * 4 + i;          // 0..2047 = t_local*16 + bt
      int tl = mt >> 4, bt = mt & 15;
      int tg = cn * TC + tl;
      const float* xp = x + ((size_t)(bt * 16 + sr) * Tsz + tg) * IN_DIM + sc;
      h8 hv;
#pragma unroll
      for (int j = 0; j < 8; j++) hv[j] = (f16)xp[j];
      *(h8*)(stg + sr * 136 + sc) = hv;
      __syncthreads();
      h8 A[4];
#pragma unroll
      for (int kt = 0; kt < 4; kt++)
        A[kt] = *(const h8*)(stg + col * 136 + kt * 32 + q * 8);
#pragma unroll
      for (int nt = 0; nt < 10; nt++) {
        f4 acc = {0.f, 0.f, 0.f, 0.f};
#pragma unroll
        for (int kt = 0; kt < 4; kt++) acc = MFMA(A[kt], Bf[nt][kt], acc);
        h4 o;
#pragma unroll
        for (int rr = 0; rr < 4; rr++) o[rr] = (f16)acc[rr];
        *(h4*)(XU0 + ((size_t)mt * NT0 + w * 10 + nt) * 256 + lane * 4) = o;
      }
      __syncthreads();
    }
  }
}

// ---------------- R: [r0(c) on WGs 0-15 | r12(c-1) on WGs 16-31] ---------------------
__global__ __launch_bounds__(640) void R_kernel(
    const h8* __restrict__ pk,
    const float* __restrict__ b1_0, const float* __restrict__ b2_0,
    const float* __restrict__ ba_0, const float* __restrict__ bb_0,
    const float* __restrict__ b1_1, const float* __restrict__ b2_1,
    const float* __restrict__ ba_1, const float* __restrict__ bb_1,
    const float* __restrict__ c1, const float* __restrict__ c2,
    const float* __restrict__ ca, const float* __restrict__ cb,
    const float* __restrict__ dtp, const f16* __restrict__ XU0,
    const f16* __restrict__ XU1, f16* __restrict__ NH0,
    f16* __restrict__ H0S, f16* __restrict__ H12S, float* __restrict__ out, int c) {
  __shared__ __align__(16) char smem[2 * 16 * S0 * 2];  // union: r0 buf / r12 buf
  int tid = threadIdx.x;
  int g = tid >> 6, lane = tid & 63, col = lane & 15, q = lane >> 4;
  int wg = blockIdx.x;

  if (wg < NBT) {  // ================= r0, chunk c =================
    if (c >= NCH) return;
    f16(*buf)[16 * S0] = (f16(*)[16 * S0])smem;
    int bt = wg;
    int n = g * 16 + col;                      // output neuron (0..159, valid <149)
    float ts = dtp[0];
    h8 Bf[4][5];                               // recurrent weights, resident across t-loop
#pragma unroll
    for (int mat = 0; mat < 4; mat++)
#pragma unroll
      for (int kt = 0; kt < 5; kt++)
        Bf[mat][kt] = pk[OFF_R0 + ((g * 4 + mat) * 5 + kt) * 64 + lane];
    float b1n = (n < Ni) ? b1_0[n] : 0.f, b2n = (n < Ni) ? b2_0[n] : 0.f;
    float ban = (n < Ni) ? ba_0[n] : 0.f, bbn = (n < Ni) ? bb_0[n] : 0.f;

    for (int idx = tid; idx < 16 * S0; idx += 640) {
      buf[0][idx] = (c == 0) ? (f16)0.f : H0S[(size_t)bt * 16 * S0 + idx];
      buf[1][idx] = (f16)0.f;
    }
    __syncthreads();

    h4 xu[4];
#pragma unroll
    for (int mat = 0; mat < 4; mat++)
      xu[mat] = *(const h4*)(XU0 + ((size_t)bt * NT0 + mat * 10 + g) * 256 + lane * 4);

    for (int t = 0; t < TC; t++) {
      const f16* br = buf[t & 1];
      f16* bw = buf[(t + 1) & 1];
      int tn = (t + 1 < TC) ? t + 1 : t;
      size_t mtn = (size_t)tn * NBT + bt;
      h4 xun[4];
#pragma unroll
      for (int mat = 0; mat < 4; mat++)
        xun[mat] = *(const h4*)(XU0 + (mtn * NT0 + mat * 10 + g) * 256 + lane * 4);
      int mt = t * NBT + bt;
      h8 A[5];
#pragma unroll
      for (int kt = 0; kt < 5; kt++)
        A[kt] = *(const h8*)(br + col * S0 + kt * 32 + q * 8);
      f4 acc0 = {0.f, 0.f, 0.f, 0.f}, acc1 = acc0, acc2 = acc0, acc3 = acc0;
#pragma unroll
      for (int kt = 0; kt < 5; kt++) {
        acc0 = MFMA(A[kt], Bf[0][kt], acc0);
        acc1 = MFMA(A[kt], Bf[1][kt], acc1);
      }
      float ff1[4], ff2[4];
#pragma unroll
      for (int r = 0; r < 4; r++) {
        float u1 = acc0[r] + (float)xu[0][r] + b1n;
        float u2 = acc1[r] + (float)xu[1][r] + b2n;
        ff1[r] = tanhf_(u1);
        ff2[r] = tanhf_(u2);
      }
#pragma unroll
      for (int kt = 0; kt < 5; kt++) {
        acc2 = MFMA(A[kt], Bf[2][kt], acc2);
        acc3 = MFMA(A[kt], Bf[3][kt], acc3);
      }
      f16* nh = NH0 + (size_t)mt * 2560;
#pragma unroll
      for (int r = 0; r < 4; r++) {
        int m = q * 4 + r;
        float ua = acc2[r] + (float)xu[2][r] + ban;
        float ub = acc3[r] + (float)xu[3][r] + bbn;
        float ti = sigm_(ua * ts + ub);
        float h = ff1[r] + (ff2[r] - ff1[r]) * ti;
        f16 h16 = (f16)h;
        bw[m * S0 + n] = h16;
        nh[m * 160 + n] = h16;
        if (c == NCH - 1 && t == TC - 1 && n < Ni)
          out[YOFF + (size_t)(bt * 16 + m) * 256 + n] = h;
      }
      RAW_BAR();
#pragma unroll
      for (int mat = 0; mat < 4; mat++) xu[mat] = xun[mat];
    }
    for (int idx = tid; idx < 16 * S0; idx += 640)
      H0S[(size_t)bt * 16 * S0 + idx] = buf[0][idx];

  } else {  // ================= r12, chunk cc = c-1 =================
    int cc = c - 1;
    if (cc < 0) return;
    f16(*buf)[16 * S2] = (f16(*)[16 * S2])smem;
    int bt = wg - NBT;
    int w = g;                                 // wave id 0..9 (8,9 idle)
    float ts = dtp[0];
    h8 Bf[4][4];
    float bn[4];
    if (w < 7) {
      int n = w * 16 + col;
#pragma unroll
      for (int mat = 0; mat < 4; mat++)
#pragma unroll
        for (int kt = 0; kt < 4; kt++)
          Bf[mat][kt] = pk[OFF_R12A + ((w * 4 + mat) * 4 + kt) * 64 + lane];
      bn[0] = (n < Nc) ? b1_1[n] : 0.f;
      bn[1] = (n < Nc) ? b2_1[n] : 0.f;
      bn[2] = (n < Nc) ? ba_1[n] : 0.f;
      bn[3] = (n < Nc) ? bb_1[n] : 0.f;
    } else if (w == 7) {
#pragma unroll
      for (int mat = 0; mat < 4; mat++)
#pragma unroll
        for (int kt = 0; kt < 4; kt++)
          Bf[mat][kt] = pk[OFF_R12B + (mat * 4 + kt) * 64 + lane];
      bn[0] = (col < Nm) ? c1[col] : 0.f;
      bn[1] = (col < Nm) ? c2[col] : 0.f;
      bn[2] = (col < Nm) ? ca[col] : 0.f;
      bn[3] = (col < Nm) ? cb[col] : 0.f;
    }
    for (int idx = tid; idx < 2 * 16 * S2; idx += 640)
      ((f16*)buf)[idx] = (cc == 0) ? (f16)0.f : H12S[(size_t)bt * 2 * 16 * S2 + idx];
    __syncthreads();

    h4 xu[4];
    if (w < 7) {
#pragma unroll
      for (int mat = 0; mat < 4; mat++)
        xu[mat] = *(const h4*)(XU1 + ((size_t)bt * NT1 + mat * 7 + w) * 256 + lane * 4);
    }

    for (int t = 0; t < TC; t++) {
      f16* br = buf[t & 1];
      f16* bw = buf[(t + 1) & 1];
      h4 xun[4];
      if (w < 7) {
        int tn = (t + 1 < TC) ? t + 1 : t;
        size_t mtn = (size_t)tn * NBT + bt;
#pragma unroll
        for (int mat = 0; mat < 4; mat++)
          xun[mat] = *(const h4*)(XU1 + (mtn * NT1 + mat * 7 + w) * 256 + lane * 4);
        int n = w * 16 + col;
        h8 A[4];
#pragma unroll
        for (int kt = 0; kt < 4; kt++)
          A[kt] = *(const h8*)(br + col * S2 + kt * 32 + q * 8);
        f4 acc0 = {0.f, 0.f, 0.f, 0.f}, acc1 = acc0, acc2 = acc0, acc3 = acc0;
#pragma unroll
        for (int kt = 0; kt < 4; kt++) {
          acc0 = MFMA(A[kt], Bf[0][kt], acc0);
          acc1 = MFMA(A[kt], Bf[1][kt], acc1);
        }
        float ff1[4], ff2[4];
#pragma unroll
        for (int r = 0; r < 4; r++) {
          float u1 = acc0[r] + (float)xu[0][r] + bn[0];
          float u2 = acc1[r] + (float)xu[1][r] + bn[1];
          ff1[r] = tanhf_(u1);
          ff2[r] = tanhf_(u2);
        }
#pragma unroll
        for (int kt = 0; kt < 4; kt++) {
          acc2 = MFMA(A[kt], Bf[2][kt], acc2);
          acc3 = MFMA(A[kt], Bf[3][kt], acc3);
        }
#pragma unroll
        for (int r = 0; r < 4; r++) {
          int m = q * 4 + r;
          float ua = acc2[r] + (float)xu[2][r] + bn[2];
          float ub = acc3[r] + (float)xu[3][r] + bn[3];
          float ti = sigm_(ua * ts + ub);
          float h = ff1[r] + (ff2[r] - ff1[r]) * ti;
          if (n < Nc) {
            bw[m * S2 + n] = (f16)h;
            if (cc == NCH - 1 && t == TC - 1)
              out[YOFF + (size_t)(bt * 16 + m) * 256 + Ni + n] = h;
          }
        }
      }
      RAW_BAR();
      if (w < 7) {
#pragma unroll
        for (int mat = 0; mat < 4; mat++) xu[mat] = xun[mat];
      }
      if (w == 7) {  // layer2(t): A = [nh1(t) | h2(t-1)] in bw; writes h2(t) into br
        int tg = cc * TC + t;
        h8 A[4];
#pragma unroll
        for (int kt = 0; kt < 4; kt++)
          A[kt] = *(const h8*)(bw + col * S2 + kt * 32 + q * 8);
        f4 acc0 = {0.f, 0.f, 0.f, 0.f}, acc1 = acc0, acc2 = acc0, acc3 = acc0;
#pragma unroll
        for (int kt = 0; kt < 4; kt++) {
          acc0 = MFMA(A[kt], Bf[0][kt], acc0);
          acc1 = MFMA(A[kt], Bf[1][kt], acc1);
          acc2 = MFMA(A[kt], Bf[2][kt], acc2);
          acc3 = MFMA(A[kt], Bf[3][kt], acc3);
        }
#pragma unroll
        for (int r = 0; r < 4; r++) {
          int m = q * 4 + r;
          float u1 = acc0[r] + bn[0];
          float u2 = acc1[r] + bn[1];
          float ua = acc2[r] + bn[2];
          float ub = acc3[r] + bn[3];
          float ff1 = tanhf_(u1), ff2 = tanhf_(u2);
          float ti = sigm_(ua * ts + ub);
          float h = ff1 + (ff2 - ff1) * ti;
          if (col < Nm) {
            out[((size_t)(bt * 16 + m) * Tsz + tg) * 8 + col] = tanhf_(h);
            br[m * S2 + Nc + col] = (f16)h;
            if (cc == NCH - 1 && t == TC - 1)
              out[YOFF + (size_t)(bt * 16 + m) * 256 + Ni + Nc + col] = h;
          }
        }
      }
    }
    __syncthreads();
    for (int idx = tid; idx < 2 * 16 * S2; idx += 640)
      H12S[(size_t)bt * 2 * 16 * S2 + idx] = ((f16*)buf)[idx];
  }
}

extern "C" void kernel_launch(void* const* d_in, const int* in_sizes, int n_in,
                              void* d_out, int out_size, void* d_ws, size_t ws_size,
                              hipStream_t stream) {
  const float* w1_0 = (const float*)d_in[0];
  const float* w2_0 = (const float*)d_in[1];
  const float* wa_0 = (const float*)d_in[2];
  const float* wb_0 = (const float*)d_in[3];
  const float* b1_0 = (const float*)d_in[4];
  const float* b2_0 = (const float*)d_in[5];
  const float* ba_0 = (const float*)d_in[6];
  const float* bb_0 = (const float*)d_in[7];
  const int* m0 = (const int*)d_in[8];
  const float* w1_1 = (const float*)d_in[9];
  const float* w2_1 = (const float*)d_in[10];
  const float* wa_1 = (const float*)d_in[11];
  const float* wb_1 = (const float*)d_in[12];
  const float* b1_1 = (const float*)d_in[13];
  const float* b2_1 = (const float*)d_in[14];
  const float* ba_1 = (const float*)d_in[15];
  const float* bb_1 = (const float*)d_in[16];
  const int* m1 = (const int*)d_in[17];
  const float* w1_2 = (const float*)d_in[18];
  const float* w2_2 = (const float*)d_in[19];
  const float* wa_2 = (const float*)d_in[20];
  const float* wb_2 = (const float*)d_in[21];
  const float* c1 = (const float*)d_in[22];
  const float* c2 = (const float*)d_in[23];
  const float* ca = (const float*)d_in[24];
  const float* cb = (const float*)d_in[25];
  const int* m2 = (const int*)d_in[26];
  const float* x = (const float*)d_in[27];
  const float* dt = (const float*)d_in[28];
  float* out = (float*)d_out;

  f16* XU0 = (f16*)d_ws;
  f16* NH0 = XU0 + XU0_HALVES;
  f16* XU1 = NH0 + NH0_HALVES;
  f16* H0S = XU1 + XU1_HALVES;
  f16* H12S = H0S + H0S_HALVES;
  f16* PK = H12S + H12S_HALVES;
  const h8* pk = (const h8*)PK;

  pack_kernel<<<(NFRAG + 255) / 256, 256, 0, stream>>>(
      w1_0, w2_0, wa_0, wb_0, m0, w1_1, w2_1, wa_1, wb_1, m1,
      w1_2, w2_2, wa_2, wb_2, m2, PK);

  // prologue: x0(0)
  X_kernel<<<1024, 256, 0, stream>>>(pk, x, NH0, XU0, XU1, -1);

  for (int c = 0; c <= NCH; c++) {
    R_kernel<<<32, 640, 0, stream>>>(pk, b1_0, b2_0, ba_0, bb_0, b1_1, b2_1, ba_1,
                                     bb_1, c1, c2, ca, cb, dt, XU0, XU1, NH0, H0S,
                                     H12S, out, c);
    if (c < NCH)
      X_kernel<<<1024, 256, 0, stream>>>(pk, x, NH0, XU0, XU1, c);
  }
}

// Round 5
// 883.423 us; speedup vs baseline: 3.2849x; 1.2340x over previous
//
#include <hip/hip_runtime.h>
#include <cmath>

// CfC-NCP RNN, phase-decomposed + chunk-pipelined:
//   pack (once): weight fragments -> h8 in ws, with (ts*wa+wb) MERGED into one
//   matrix (ts = dt[0] read on device) -> 3 matrices per cell instead of 4.
//   Biases (incl ts*ba+bb) folded into XU by the x-kernels' epilogues.
//   X(-1): x0(0).  c=0..4: R(c) = [r0(c) WGs 0-15 | r12(c-1) WGs 16-31];
//   c<4: X(c) = [x1(c) WGs 0-511 | x0(c+1) WGs 512-1023].
// fp16 MFMA inputs, fp32 accum. Workspace ~65 MB.
// R1: XU prefetch + raw lgkmcnt-only barrier. R2: packed weights + MFMA/epilogue
// interleave. R3: WG-split pipelining. R4: wa/wb merge (MFMA -25%, XU -25%),
// bias folding + acc-init-from-xu (epilogue VALU cut).

typedef _Float16 f16;
typedef f16 h4 __attribute__((ext_vector_type(4)));
typedef f16 h8 __attribute__((ext_vector_type(8)));
typedef float f4 __attribute__((ext_vector_type(4)));

#define MFMA(a, b, c) __builtin_amdgcn_mfma_f32_16x16x32_f16(a, b, c, 0, 0, 0)
// LDS-only barrier: waves drain their own LDS ops (lgkmcnt) then sync; global ops
// (XU prefetch loads, NH0/y stores) intentionally left in flight.
#define RAW_BAR() asm volatile("s_waitcnt lgkmcnt(0)\n\ts_barrier" ::: "memory")

constexpr int IN_DIM = 128, Ni = 149, Nc = 99, Nm = 8;
constexpr int CAT0 = 277, CAT1 = 248, CAT2 = 107;
constexpr int Bsz = 256, Tsz = 512;
constexpr int TC = 128, NCH = 4, NBT = 16;
constexpr int NT0 = 30, NT1 = 21;        // fragment tile-columns (3 mats x n-tiles)
constexpr int S0 = 168, S2 = 136;        // LDS row strides (halves), bank-conflict pad
constexpr size_t XU0_HALVES = (size_t)TC * NBT * NT0 * 256;  // 15,728,640
constexpr size_t NH0_HALVES = (size_t)TC * NBT * 16 * 160;   //  5,242,880
constexpr size_t XU1_HALVES = (size_t)TC * NBT * NT1 * 256;  // 11,010,048
constexpr size_t H0S_HALVES = (size_t)NBT * 16 * S0;
constexpr size_t H12S_HALVES = (size_t)NBT * 2 * 16 * S2;
constexpr size_t YOFF = (size_t)Bsz * Tsz * 8;  // h_out offset in d_out

// packed-fragment segment offsets (h8 units); mat2 = merged ts*wa+wb
constexpr int OFF_X0 = 0;          // [mat3][nt10][kt4][lane64]
constexpr int OFF_R0 = 7680;       // [g10][mat3][kt5][lane64]
constexpr int OFF_X1 = 17280;      // [mat3][nt7][kt5][lane64]
constexpr int OFF_R12A = 24000;    // [w7][mat3][kt4][lane64]
constexpr int OFF_R12B = 29376;    // [mat3][kt4][lane64]
constexpr int NFRAG = 30144;

__device__ inline float rcpf_(float x) { return __builtin_amdgcn_rcpf(x); }
__device__ inline float tanhf_(float x) {
  float e = __expf(-2.f * fabsf(x));          // in (0,1], no overflow
  float t = (1.f - e) * rcpf_(1.f + e);
  return x < 0.f ? -t : t;
}
__device__ inline float sigm_(float z) { return rcpf_(1.f + __expf(-z)); }

// ---------------- pack: build all h8 weight fragments once per call ------------------
__global__ __launch_bounds__(256) void pack_kernel(
    const float* __restrict__ w1_0, const float* __restrict__ w2_0,
    const float* __restrict__ wa_0, const float* __restrict__ wb_0,
    const int* __restrict__ m0,
    const float* __restrict__ w1_1, const float* __restrict__ w2_1,
    const float* __restrict__ wa_1, const float* __restrict__ wb_1,
    const int* __restrict__ m1,
    const float* __restrict__ w1_2, const float* __restrict__ w2_2,
    const float* __restrict__ wa_2, const float* __restrict__ wb_2,
    const int* __restrict__ m2, const float* __restrict__ dtp,
    f16* __restrict__ PK) {
  int idx = blockIdx.x * 256 + threadIdx.x;
  if (idx >= NFRAG) return;
  int lane = idx & 63, col = lane & 15, q = lane >> 4;
  float ts = dtp[0];
  const float* Wa = nullptr;
  const float* Wb = nullptr;
  const int* M = nullptr;
  int ld, n, nmax, k0, kmax;
  if (idx < OFF_R0) {  // x0 input-part
    int p = idx >> 6;
    int mat = p / 40, nt = (p >> 2) % 10, kt = p & 3;
    ld = CAT0; n = nt * 16 + col; nmax = Ni; k0 = kt * 32 + q * 8; kmax = IN_DIM;
    if (mat == 0) { Wa = w1_0; M = m0; }
    else if (mat == 1) { Wa = w2_0; M = m0; }
    else { Wa = wa_0; Wb = wb_0; }
  } else if (idx < OFF_X1) {  // r0 recurrent-part
    int p = (idx - OFF_R0) >> 6;
    int g = p / 15, mat = (p / 5) % 3, kt = p % 5;
    ld = CAT0; n = g * 16 + col; nmax = Ni; k0 = IN_DIM + kt * 32 + q * 8; kmax = CAT0;
    if (mat == 0) Wa = w1_0;
    else if (mat == 1) Wa = w2_0;
    else { Wa = wa_0; Wb = wb_0; }
  } else if (idx < OFF_R12A) {  // x1 input-part
    int p = (idx - OFF_X1) >> 6;
    int mat = p / 35, nt = (p / 5) % 7, kt = p % 5;
    ld = CAT1; n = nt * 16 + col; nmax = Nc; k0 = kt * 32 + q * 8; kmax = Ni;
    if (mat == 0) { Wa = w1_1; M = m1; }
    else if (mat == 1) { Wa = w2_1; M = m1; }
    else { Wa = wa_1; Wb = wb_1; }
  } else if (idx < OFF_R12B) {  // r12 layer1 recurrent-part
    int p = (idx - OFF_R12A) >> 6;
    int wv = p / 12, mat = (p / 4) % 3, kt = p & 3;
    ld = CAT1; n = wv * 16 + col; nmax = Nc; k0 = Ni + kt * 32 + q * 8; kmax = CAT1;
    if (mat == 0) Wa = w1_1;
    else if (mat == 1) Wa = w2_1;
    else { Wa = wa_1; Wb = wb_1; }
  } else {  // r12 layer2 (full cat)
    int p = (idx - OFF_R12B) >> 6;
    int mat = p / 4, kt = p & 3;
    ld = CAT2; n = col; nmax = Nm; k0 = kt * 32 + q * 8; kmax = CAT2;
    if (mat == 0) { Wa = w1_2; M = m2; }
    else if (mat == 1) { Wa = w2_2; M = m2; }
    else { Wa = wa_2; Wb = wb_2; }
  }
  h8 r;
#pragma unroll
  for (int j = 0; j < 8; j++) {
    int k = k0 + j;
    float v = 0.f;
    if (n < nmax && k < kmax) {
      v = Wa[(size_t)n * ld + k];
      if (Wb) v = ts * v + Wb[(size_t)n * ld + k];
      if (M) v *= (float)M[(size_t)n * ld + k];
    }
    r[j] = (f16)v;
  }
  ((h8*)PK)[idx] = r;
}

// ---------------- X: [x1(c) | x0(c+1)] on disjoint WG ranges, 3 waves/WG -------------
__global__ __launch_bounds__(192, 2) void X_kernel(
    const h8* __restrict__ pk, const float* __restrict__ x,
    const f16* __restrict__ NH0, f16* __restrict__ XU0, f16* __restrict__ XU1,
    const float* __restrict__ b1_0, const float* __restrict__ b2_0,
    const float* __restrict__ ba_0, const float* __restrict__ bb_0,
    const float* __restrict__ b1_1, const float* __restrict__ b2_1,
    const float* __restrict__ ba_1, const float* __restrict__ bb_1,
    const float* __restrict__ dtp, int c) {
  __shared__ f16 stg[16 * 136];
  int tid = threadIdx.x;
  int w = tid >> 6, lane = tid & 63, col = lane & 15, q = lane >> 4;
  int wg = blockIdx.x;
  float ts = dtp[0];
  if (wg < 512) {  // ---- x1 for chunk c (wave w = mat) ----
    if (c < 0) return;
    h8 Bf[7][5];
    float bias[7];
#pragma unroll
    for (int nt = 0; nt < 7; nt++) {
#pragma unroll
      for (int kt = 0; kt < 5; kt++)
        Bf[nt][kt] = pk[OFF_X1 + ((w * 7 + nt) * 5 + kt) * 64 + lane];
      int n = nt * 16 + col;
      bias[nt] = (n < Nc) ? (w == 0 ? b1_1[n]
                                    : (w == 1 ? b2_1[n] : ts * ba_1[n] + bb_1[n]))
                          : 0.f;
    }
    for (int i = 0; i < 4; i++) {
      int mt = wg * 4 + i;
      const f16* Ab = NH0 + (size_t)mt * 2560;  // 16x160 halves; pad cols are zero
      h8 A[5];
#pragma unroll
      for (int kt = 0; kt < 5; kt++)
        A[kt] = *(const h8*)(Ab + col * 160 + kt * 32 + q * 8);
#pragma unroll
      for (int nt = 0; nt < 7; nt++) {
        float b = bias[nt];
        f4 acc = {b, b, b, b};
#pragma unroll
        for (int kt = 0; kt < 5; kt++) acc = MFMA(A[kt], Bf[nt][kt], acc);
        h4 o;
#pragma unroll
        for (int rr = 0; rr < 4; rr++) o[rr] = (f16)acc[rr];
        *(h4*)(XU1 + ((size_t)mt * NT1 + w * 7 + nt) * 256 + lane * 4) = o;
      }
    }
  } else {  // ---- x0 for chunk c+1 (wave w = mat) ----
    int cn = c + 1;
    if (cn >= NCH) return;
    int bx = wg - 512;
    h8 Bf[10][4];
    float bias[10];
#pragma unroll
    for (int nt = 0; nt < 10; nt++) {
#pragma unroll
      for (int kt = 0; kt < 4; kt++)
        Bf[nt][kt] = pk[OFF_X0 + ((w * 10 + nt) * 4 + kt) * 64 + lane];
      int n = nt * 16 + col;
      bias[nt] = (n < Ni) ? (w == 0 ? b1_0[n]
                                    : (w == 1 ? b2_0[n] : ts * ba_0[n] + bb_0[n]))
                          : 0.f;
    }
    for (int i = 0; i < 4; i++) {
      int mt = bx * 4 + i;          // 0..2047 = t_local*16 + bt
      int tl = mt >> 4, bt = mt & 15;
      int tg = cn * TC + tl;
      if (tid < 128) {
        int sr = tid >> 3, sc = (tid & 7) * 16;
        const float* xp = x + ((size_t)(bt * 16 + sr) * Tsz + tg) * IN_DIM + sc;
        h8 hv0, hv1;
#pragma unroll
        for (int j = 0; j < 8; j++) hv0[j] = (f16)xp[j];
#pragma unroll
        for (int j = 0; j < 8; j++) hv1[j] = (f16)xp[8 + j];
        *(h8*)(stg + sr * 136 + sc) = hv0;
        *(h8*)(stg + sr * 136 + sc + 8) = hv1;
      }
      __syncthreads();
      h8 A[4];
#pragma unroll
      for (int kt = 0; kt < 4; kt++)
        A[kt] = *(const h8*)(stg + col * 136 + kt * 32 + q * 8);
#pragma unroll
      for (int nt = 0; nt < 10; nt++) {
        float b = bias[nt];
        f4 acc = {b, b, b, b};
#pragma unroll
        for (int kt = 0; kt < 4; kt++) acc = MFMA(A[kt], Bf[nt][kt], acc);
        h4 o;
#pragma unroll
        for (int rr = 0; rr < 4; rr++) o[rr] = (f16)acc[rr];
        *(h4*)(XU0 + ((size_t)mt * NT0 + w * 10 + nt) * 256 + lane * 4) = o;
      }
      __syncthreads();
    }
  }
}

// ---------------- R: [r0(c) on WGs 0-15 | r12(c-1) on WGs 16-31] ---------------------
__global__ __launch_bounds__(640) void R_kernel(
    const h8* __restrict__ pk,
    const float* __restrict__ c1, const float* __restrict__ c2,
    const float* __restrict__ ca, const float* __restrict__ cb,
    const float* __restrict__ dtp, const f16* __restrict__ XU0,
    const f16* __restrict__ XU1, f16* __restrict__ NH0,
    f16* __restrict__ H0S, f16* __restrict__ H12S, float* __restrict__ out, int c) {
  __shared__ __align__(16) char smem[2 * 16 * S0 * 2];  // union: r0 buf / r12 buf
  int tid = threadIdx.x;
  int g = tid >> 6, lane = tid & 63, col = lane & 15, q = lane >> 4;
  int wg = blockIdx.x;

  if (wg < NBT) {  // ================= r0, chunk c =================
    if (c >= NCH) return;
    f16(*buf)[16 * S0] = (f16(*)[16 * S0])smem;
    int bt = wg;
    int n = g * 16 + col;                      // output neuron (0..159, valid <149)
    h8 Bf[3][5];                               // recurrent weights, resident across t-loop
#pragma unroll
    for (int mat = 0; mat < 3; mat++)
#pragma unroll
      for (int kt = 0; kt < 5; kt++)
        Bf[mat][kt] = pk[OFF_R0 + ((g * 3 + mat) * 5 + kt) * 64 + lane];

    for (int idx = tid; idx < 16 * S0; idx += 640) {
      buf[0][idx] = (c == 0) ? (f16)0.f : H0S[(size_t)bt * 16 * S0 + idx];
      buf[1][idx] = (f16)0.f;
    }
    __syncthreads();

    h4 xu[3];
#pragma unroll
    for (int mat = 0; mat < 3; mat++)
      xu[mat] = *(const h4*)(XU0 + ((size_t)bt * NT0 + mat * 10 + g) * 256 + lane * 4);

    for (int t = 0; t < TC; t++) {
      const f16* br = buf[t & 1];
      f16* bw = buf[(t + 1) & 1];
      int tn = (t + 1 < TC) ? t + 1 : t;
      size_t mtn = (size_t)tn * NBT + bt;
      h4 xun[3];
#pragma unroll
      for (int mat = 0; mat < 3; mat++)
        xun[mat] = *(const h4*)(XU0 + (mtn * NT0 + mat * 10 + g) * 256 + lane * 4);
      int mt = t * NBT + bt;
      h8 A[5];
#pragma unroll
      for (int kt = 0; kt < 5; kt++)
        A[kt] = *(const h8*)(br + col * S0 + kt * 32 + q * 8);
      f4 acc0 = {(float)xu[0][0], (float)xu[0][1], (float)xu[0][2], (float)xu[0][3]};
      f4 acc1 = {(float)xu[1][0], (float)xu[1][1], (float)xu[1][2], (float)xu[1][3]};
#pragma unroll
      for (int kt = 0; kt < 5; kt++) {
        acc0 = MFMA(A[kt], Bf[0][kt], acc0);
        acc1 = MFMA(A[kt], Bf[1][kt], acc1);
      }
      float ff1[4], ff2[4];
#pragma unroll
      for (int r = 0; r < 4; r++) {
        ff1[r] = tanhf_(acc0[r]);
        ff2[r] = tanhf_(acc1[r]);
      }
      f4 acc2 = {(float)xu[2][0], (float)xu[2][1], (float)xu[2][2], (float)xu[2][3]};
#pragma unroll
      for (int kt = 0; kt < 5; kt++) acc2 = MFMA(A[kt], Bf[2][kt], acc2);
      f16* nh = NH0 + (size_t)mt * 2560;
#pragma unroll
      for (int r = 0; r < 4; r++) {
        int m = q * 4 + r;
        float ti = sigm_(acc2[r]);
        float h = ff1[r] + (ff2[r] - ff1[r]) * ti;
        f16 h16 = (f16)h;
        bw[m * S0 + n] = h16;
        nh[m * 160 + n] = h16;
        if (c == NCH - 1 && t == TC - 1 && n < Ni)
          out[YOFF + (size_t)(bt * 16 + m) * 256 + n] = h;
      }
      RAW_BAR();
#pragma unroll
      for (int mat = 0; mat < 3; mat++) xu[mat] = xun[mat];
    }
    for (int idx = tid; idx < 16 * S0; idx += 640)
      H0S[(size_t)bt * 16 * S0 + idx] = buf[0][idx];

  } else {  // ================= r12, chunk cc = c-1 =================
    int cc = c - 1;
    if (cc < 0) return;
    f16(*buf)[16 * S2] = (f16(*)[16 * S2])smem;
    int bt = wg - NBT;
    int w = g;                                 // wave id 0..9 (8,9 idle)
    float ts = dtp[0];
    h8 Bf[3][4];
    float bn0 = 0.f, bn1 = 0.f, bn2 = 0.f;
    if (w < 7) {
#pragma unroll
      for (int mat = 0; mat < 3; mat++)
#pragma unroll
        for (int kt = 0; kt < 4; kt++)
          Bf[mat][kt] = pk[OFF_R12A + ((w * 3 + mat) * 4 + kt) * 64 + lane];
    } else if (w == 7) {
#pragma unroll
      for (int mat = 0; mat < 3; mat++)
#pragma unroll
        for (int kt = 0; kt < 4; kt++)
          Bf[mat][kt] = pk[OFF_R12B + (mat * 4 + kt) * 64 + lane];
      bn0 = (col < Nm) ? c1[col] : 0.f;
      bn1 = (col < Nm) ? c2[col] : 0.f;
      bn2 = (col < Nm) ? ts * ca[col] + cb[col] : 0.f;
    }
    for (int idx = tid; idx < 2 * 16 * S2; idx += 640)
      ((f16*)buf)[idx] = (cc == 0) ? (f16)0.f : H12S[(size_t)bt * 2 * 16 * S2 + idx];
    __syncthreads();

    h4 xu[3];
    if (w < 7) {
#pragma unroll
      for (int mat = 0; mat < 3; mat++)
        xu[mat] = *(const h4*)(XU1 + ((size_t)bt * NT1 + mat * 7 + w) * 256 + lane * 4);
    }

    for (int t = 0; t < TC; t++) {
      f16* br = buf[t & 1];
      f16* bw = buf[(t + 1) & 1];
      h4 xun[3];
      if (w < 7) {
        int tn = (t + 1 < TC) ? t + 1 : t;
        size_t mtn = (size_t)tn * NBT + bt;
#pragma unroll
        for (int mat = 0; mat < 3; mat++)
          xun[mat] = *(const h4*)(XU1 + (mtn * NT1 + mat * 7 + w) * 256 + lane * 4);
        int n = w * 16 + col;
        h8 A[4];
#pragma unroll
        for (int kt = 0; kt < 4; kt++)
          A[kt] = *(const h8*)(br + col * S2 + kt * 32 + q * 8);
        f4 acc0 = {(float)xu[0][0], (float)xu[0][1], (float)xu[0][2], (float)xu[0][3]};
        f4 acc1 = {(float)xu[1][0], (float)xu[1][1], (float)xu[1][2], (float)xu[1][3]};
#pragma unroll
        for (int kt = 0; kt < 4; kt++) {
          acc0 = MFMA(A[kt], Bf[0][kt], acc0);
          acc1 = MFMA(A[kt], Bf[1][kt], acc1);
        }
        float ff1[4], ff2[4];
#pragma unroll
        for (int r = 0; r < 4; r++) {
          ff1[r] = tanhf_(acc0[r]);
          ff2[r] = tanhf_(acc1[r]);
        }
        f4 acc2 = {(float)xu[2][0], (float)xu[2][1], (float)xu[2][2], (float)xu[2][3]};
#pragma unroll
        for (int kt = 0; kt < 4; kt++) acc2 = MFMA(A[kt], Bf[2][kt], acc2);
#pragma unroll
        for (int r = 0; r < 4; r++) {
          int m = q * 4 + r;
          float ti = sigm_(acc2[r]);
          float h = ff1[r] + (ff2[r] - ff1[r]) * ti;
          if (n < Nc) {
            bw[m * S2 + n] = (f16)h;
            if (cc == NCH - 1 && t == TC - 1)
              out[YOFF + (size_t)(bt * 16 + m) * 256 + Ni + n] = h;
          }
        }
      }
      RAW_BAR();
      if (w < 7) {
#pragma unroll
        for (int mat = 0; mat < 3; mat++) xu[mat] = xun[mat];
      }
      if (w == 7) {  // layer2(t): A = [nh1(t) | h2(t-1)] in bw; writes h2(t) into br
        int tg = cc * TC + t;
        h8 A[4];
#pragma unroll
        for (int kt = 0; kt < 4; kt++)
          A[kt] = *(const h8*)(bw + col * S2 + kt * 32 + q * 8);
        f4 acc0 = {bn0, bn0, bn0, bn0};
        f4 acc1 = {bn1, bn1, bn1, bn1};
        f4 acc2 = {bn2, bn2, bn2, bn2};
#pragma unroll
        for (int kt = 0; kt < 4; kt++) {
          acc0 = MFMA(A[kt], Bf[0][kt], acc0);
          acc1 = MFMA(A[kt], Bf[1][kt], acc1);
          acc2 = MFMA(A[kt], Bf[2][kt], acc2);
        }
#pragma unroll
        for (int r = 0; r < 4; r++) {
          int m = q * 4 + r;
          float ff1 = tanhf_(acc0[r]), ff2 = tanhf_(acc1[r]);
          float ti = sigm_(acc2[r]);
          float h = ff1 + (ff2 - ff1) * ti;
          if (col < Nm) {
            out[((size_t)(bt * 16 + m) * Tsz + tg) * 8 + col] = tanhf_(h);
            br[m * S2 + Nc + col] = (f16)h;
            if (cc == NCH - 1 && t == TC - 1)
              out[YOFF + (size_t)(bt * 16 + m) * 256 + Ni + Nc + col] = h;
          }
        }
      }
    }
    __syncthreads();
    for (int idx = tid; idx < 2 * 16 * S2; idx += 640)
      H12S[(size_t)bt * 2 * 16 * S2 + idx] = ((f16*)buf)[idx];
  }
}

extern "C" void kernel_launch(void* const* d_in, const int* in_sizes, int n_in,
                              void* d_out, int out_size, void* d_ws, size_t ws_size,
                              hipStream_t stream) {
  const float* w1_0 = (const float*)d_in[0];
  const float* w2_0 = (const float*)d_in[1];
  const float* wa_0 = (const float*)d_in[2];
  const float* wb_0 = (const float*)d_in[3];
  const float* b1_0 = (const float*)d_in[4];
  const float* b2_0 = (const float*)d_in[5];
  const float* ba_0 = (const float*)d_in[6];
  const float* bb_0 = (const float*)d_in[7];
  const int* m0 = (const int*)d_in[8];
  const float* w1_1 = (const float*)d_in[9];
  const float* w2_1 = (const float*)d_in[10];
  const float* wa_1 = (const float*)d_in[11];
  const float* wb_1 = (const float*)d_in[12];
  const float* b1_1 = (const float*)d_in[13];
  const float* b2_1 = (const float*)d_in[14];
  const float* ba_1 = (const float*)d_in[15];
  const float* bb_1 = (const float*)d_in[16];
  const int* m1 = (const int*)d_in[17];
  const float* w1_2 = (const float*)d_in[18];
  const float* w2_2 = (const float*)d_in[19];
  const float* wa_2 = (const float*)d_in[20];
  const float* wb_2 = (const float*)d_in[21];
  const float* c1 = (const float*)d_in[22];
  const float* c2 = (const float*)d_in[23];
  const float* ca = (const float*)d_in[24];
  const float* cb = (const float*)d_in[25];
  const int* m2 = (const int*)d_in[26];
  const float* x = (const float*)d_in[27];
  const float* dt = (const float*)d_in[28];
  float* out = (float*)d_out;

  f16* XU0 = (f16*)d_ws;
  f16* NH0 = XU0 + XU0_HALVES;
  f16* XU1 = NH0 + NH0_HALVES;
  f16* H0S = XU1 + XU1_HALVES;
  f16* H12S = H0S + H0S_HALVES;
  f16* PK = H12S + H12S_HALVES;
  const h8* pk = (const h8*)PK;

  pack_kernel<<<(NFRAG + 255) / 256, 256, 0, stream>>>(
      w1_0, w2_0, wa_0, wb_0, m0, w1_1, w2_1, wa_1, wb_1, m1,
      w1_2, w2_2, wa_2, wb_2, m2, dt, PK);

  // prologue: x0(0)
  X_kernel<<<1024, 192, 0, stream>>>(pk, x, NH0, XU0, XU1, b1_0, b2_0, ba_0, bb_0,
                                     b1_1, b2_1, ba_1, bb_1, dt, -1);

  for (int c = 0; c <= NCH; c++) {
    R_kernel<<<32, 640, 0, stream>>>(pk, c1, c2, ca, cb, dt, XU0, XU1, NH0, H0S,
                                     H12S, out, c);
    if (c < NCH)
      X_kernel<<<1024, 192, 0, stream>>>(pk, x, NH0, XU0, XU1, b1_0, b2_0, ba_0,
                                         bb_0, b1_1, b2_1, ba_1, bb_1, dt, c);
  }
}

// Round 6
// 826.897 us; speedup vs baseline: 3.5095x; 1.0684x over previous
//
#include <hip/hip_runtime.h>
#include <cmath>

// CfC-NCP RNN, phase-decomposed + chunk-pipelined:
//   pack (once): weight fragments -> h8 in ws; mat2 = -(ts*wa+wb) merged, mats 0/1
//   pre-scaled by -2 so the epilogue needs no argument scaling (acc0=-2u1, acc2=-z).
//   X(-1): x0(0).  c=0..4: R(c) = [r0(c) WGs 0-15 | r12(c-1) WGs 16-31];
//   c<4: X(c) = [x1(c) WGs 0-511 | x0(c+1) WGs 512-1023].
// fp16 MFMA inputs, fp32 accum. Workspace ~65 MB.
// R1: XU prefetch + raw lgkmcnt-only barrier. R2: packed weights + pipe interleave.
// R3: WG-split pipelining. R4: wa/wb merge + bias folding.
// R5: (a) depth-2 XU prefetch via 2x loop unroll with alternating register sets
//     (no xu register copy -> no same-step vmcnt wait on the critical path);
//     (b) single-rcp epilogue h=[(1-a)(1+b)c+(1-b)(1+a)]/[(1+a)(1+b)(1+c)],
//     a,b,c=exp(acc) with scales pre-folded into weights (cuts 2 rcp + sign logic).

typedef _Float16 f16;
typedef f16 h4 __attribute__((ext_vector_type(4)));
typedef f16 h8 __attribute__((ext_vector_type(8)));
typedef float f4 __attribute__((ext_vector_type(4)));

#define MFMA(a, b, c) __builtin_amdgcn_mfma_f32_16x16x32_f16(a, b, c, 0, 0, 0)
// LDS-only barrier: waves drain their own LDS ops (lgkmcnt) then sync; global ops
// (XU prefetch loads, NH0/y stores) intentionally left in flight.
#define RAW_BAR() asm volatile("s_waitcnt lgkmcnt(0)\n\ts_barrier" ::: "memory")

constexpr int IN_DIM = 128, Ni = 149, Nc = 99, Nm = 8;
constexpr int CAT0 = 277, CAT1 = 248, CAT2 = 107;
constexpr int Bsz = 256, Tsz = 512;
constexpr int TC = 128, NCH = 4, NBT = 16;
constexpr int NT0 = 30, NT1 = 21;        // fragment tile-columns (3 mats x n-tiles)
constexpr int S0 = 168, S2 = 136;        // LDS row strides (halves), bank-conflict pad
constexpr size_t XU0_HALVES = (size_t)TC * NBT * NT0 * 256;  // 15,728,640
constexpr size_t NH0_HALVES = (size_t)TC * NBT * 16 * 160;   //  5,242,880
constexpr size_t XU1_HALVES = (size_t)TC * NBT * NT1 * 256;  // 11,010,048
constexpr size_t H0S_HALVES = (size_t)NBT * 16 * S0;
constexpr size_t H12S_HALVES = (size_t)NBT * 2 * 16 * S2;
constexpr size_t YOFF = (size_t)Bsz * Tsz * 8;  // h_out offset in d_out

// packed-fragment segment offsets (h8 units); mat2 = merged -(ts*wa+wb)
constexpr int OFF_X0 = 0;          // [mat3][nt10][kt4][lane64]
constexpr int OFF_R0 = 7680;       // [g10][mat3][kt5][lane64]
constexpr int OFF_X1 = 17280;      // [mat3][nt7][kt5][lane64]
constexpr int OFF_R12A = 24000;    // [w7][mat3][kt4][lane64]
constexpr int OFF_R12B = 29376;    // [mat3][kt4][lane64]
constexpr int NFRAG = 30144;

__device__ inline float rcpf_(float x) { return __builtin_amdgcn_rcpf(x); }
// h = ff1 + (ff2-ff1)*ti with ff=(1-e)/(1+e), ti=1/(1+c); a0=-2u1, a1=-2u2, a2=-z.
__device__ __forceinline__ float cfc_h(float a0, float a1, float a2) {
  float e0 = __expf(a0), e1 = __expf(a1), e2 = __expf(a2);
  float pa = 1.f + e0, ma = 1.f - e0;
  float pb = 1.f + e1, mb = 1.f - e1;
  float pc = 1.f + e2;
  float num = fmaf(ma * pb, e2, mb * pa);
  return num * rcpf_(pa * pb * pc);
}
__device__ __forceinline__ float tanhp_(float x) {  // tanh(x)
  float e = __expf(-2.f * x);
  return (1.f - e) * rcpf_(1.f + e);
}

// ---------------- pack: build all h8 weight fragments once per call ------------------
__global__ __launch_bounds__(256) void pack_kernel(
    const float* __restrict__ w1_0, const float* __restrict__ w2_0,
    const float* __restrict__ wa_0, const float* __restrict__ wb_0,
    const int* __restrict__ m0,
    const float* __restrict__ w1_1, const float* __restrict__ w2_1,
    const float* __restrict__ wa_1, const float* __restrict__ wb_1,
    const int* __restrict__ m1,
    const float* __restrict__ w1_2, const float* __restrict__ w2_2,
    const float* __restrict__ wa_2, const float* __restrict__ wb_2,
    const int* __restrict__ m2, const float* __restrict__ dtp,
    f16* __restrict__ PK) {
  int idx = blockIdx.x * 256 + threadIdx.x;
  if (idx >= NFRAG) return;
  int lane = idx & 63, col = lane & 15, q = lane >> 4;
  float ts = dtp[0];
  const float* Wa = nullptr;
  const float* Wb = nullptr;
  const int* M = nullptr;
  int ld, n, nmax, k0, kmax;
  int mat;
  if (idx < OFF_R0) {  // x0 input-part
    int p = idx >> 6;
    mat = p / 40; int nt = (p >> 2) % 10, kt = p & 3;
    ld = CAT0; n = nt * 16 + col; nmax = Ni; k0 = kt * 32 + q * 8; kmax = IN_DIM;
    if (mat == 0) { Wa = w1_0; M = m0; }
    else if (mat == 1) { Wa = w2_0; M = m0; }
    else { Wa = wa_0; Wb = wb_0; }
  } else if (idx < OFF_X1) {  // r0 recurrent-part
    int p = (idx - OFF_R0) >> 6;
    int g = p / 15; mat = (p / 5) % 3; int kt = p % 5;
    ld = CAT0; n = g * 16 + col; nmax = Ni; k0 = IN_DIM + kt * 32 + q * 8; kmax = CAT0;
    if (mat == 0) Wa = w1_0;
    else if (mat == 1) Wa = w2_0;
    else { Wa = wa_0; Wb = wb_0; }
  } else if (idx < OFF_R12A) {  // x1 input-part
    int p = (idx - OFF_X1) >> 6;
    mat = p / 35; int nt = (p / 5) % 7, kt = p % 5;
    ld = CAT1; n = nt * 16 + col; nmax = Nc; k0 = kt * 32 + q * 8; kmax = Ni;
    if (mat == 0) { Wa = w1_1; M = m1; }
    else if (mat == 1) { Wa = w2_1; M = m1; }
    else { Wa = wa_1; Wb = wb_1; }
  } else if (idx < OFF_R12B) {  // r12 layer1 recurrent-part
    int p = (idx - OFF_R12A) >> 6;
    int wv = p / 12; mat = (p / 4) % 3; int kt = p & 3;
    ld = CAT1; n = wv * 16 + col; nmax = Nc; k0 = Ni + kt * 32 + q * 8; kmax = CAT1;
    if (mat == 0) Wa = w1_1;
    else if (mat == 1) Wa = w2_1;
    else { Wa = wa_1; Wb = wb_1; }
  } else {  // r12 layer2 (full cat)
    int p = (idx - OFF_R12B) >> 6;
    mat = p / 4; int kt = p & 3;
    ld = CAT2; n = col; nmax = Nm; k0 = kt * 32 + q * 8; kmax = CAT2;
    if (mat == 0) { Wa = w1_2; M = m2; }
    else if (mat == 1) { Wa = w2_2; M = m2; }
    else { Wa = wa_2; Wb = wb_2; }
  }
  h8 r;
#pragma unroll
  for (int j = 0; j < 8; j++) {
    int k = k0 + j;
    float v = 0.f;
    if (n < nmax && k < kmax) {
      if (mat < 2) {
        v = Wa[(size_t)n * ld + k];
        if (M) v *= (float)M[(size_t)n * ld + k];
        v *= -2.f;                       // ff pre-scale: acc = -2u
      } else {
        v = -(ts * Wa[(size_t)n * ld + k] + Wb[(size_t)n * ld + k]);  // acc = -z
      }
    }
    r[j] = (f16)v;
  }
  ((h8*)PK)[idx] = r;
}

// ---------------- X: [x1(c) | x0(c+1)] on disjoint WG ranges, 3 waves/WG -------------
__global__ __launch_bounds__(192, 2) void X_kernel(
    const h8* __restrict__ pk, const float* __restrict__ x,
    const f16* __restrict__ NH0, f16* __restrict__ XU0, f16* __restrict__ XU1,
    const float* __restrict__ b1_0, const float* __restrict__ b2_0,
    const float* __restrict__ ba_0, const float* __restrict__ bb_0,
    const float* __restrict__ b1_1, const float* __restrict__ b2_1,
    const float* __restrict__ ba_1, const float* __restrict__ bb_1,
    const float* __restrict__ dtp, int c) {
  __shared__ f16 stg[16 * 136];
  int tid = threadIdx.x;
  int w = tid >> 6, lane = tid & 63, col = lane & 15, q = lane >> 4;
  int wg = blockIdx.x;
  float ts = dtp[0];
  if (wg < 512) {  // ---- x1 for chunk c (wave w = mat) ----
    if (c < 0) return;
    h8 Bf[7][5];
    float bias[7];
#pragma unroll
    for (int nt = 0; nt < 7; nt++) {
#pragma unroll
      for (int kt = 0; kt < 5; kt++)
        Bf[nt][kt] = pk[OFF_X1 + ((w * 7 + nt) * 5 + kt) * 64 + lane];
      int n = nt * 16 + col;
      bias[nt] = (n < Nc) ? (w == 0 ? -2.f * b1_1[n]
                                    : (w == 1 ? -2.f * b2_1[n]
                                              : -(ts * ba_1[n] + bb_1[n])))
                          : 0.f;
    }
    for (int i = 0; i < 4; i++) {
      int mt = wg * 4 + i;
      const f16* Ab = NH0 + (size_t)mt * 2560;  // 16x160 halves; pad cols are zero
      h8 A[5];
#pragma unroll
      for (int kt = 0; kt < 5; kt++)
        A[kt] = *(const h8*)(Ab + col * 160 + kt * 32 + q * 8);
#pragma unroll
      for (int nt = 0; nt < 7; nt++) {
        float b = bias[nt];
        f4 acc = {b, b, b, b};
#pragma unroll
        for (int kt = 0; kt < 5; kt++) acc = MFMA(A[kt], Bf[nt][kt], acc);
        h4 o;
#pragma unroll
        for (int rr = 0; rr < 4; rr++) o[rr] = (f16)acc[rr];
        *(h4*)(XU1 + ((size_t)mt * NT1 + w * 7 + nt) * 256 + lane * 4) = o;
      }
    }
  } else {  // ---- x0 for chunk c+1 (wave w = mat) ----
    int cn = c + 1;
    if (cn >= NCH) return;
    int bx = wg - 512;
    h8 Bf[10][4];
    float bias[10];
#pragma unroll
    for (int nt = 0; nt < 10; nt++) {
#pragma unroll
      for (int kt = 0; kt < 4; kt++)
        Bf[nt][kt] = pk[OFF_X0 + ((w * 10 + nt) * 4 + kt) * 64 + lane];
      int n = nt * 16 + col;
      bias[nt] = (n < Ni) ? (w == 0 ? -2.f * b1_0[n]
                                    : (w == 1 ? -2.f * b2_0[n]
                                              : -(ts * ba_0[n] + bb_0[n])))
                          : 0.f;
    }
    for (int i = 0; i < 4; i++) {
      int mt = bx * 4 + i;          // 0..2047 = t_local*16 + bt
      int tl = mt >> 4, bt = mt & 15;
      int tg = cn * TC + tl;
      if (tid < 128) {
        int sr = tid >> 3, sc = (tid & 7) * 16;
        const float* xp = x + ((size_t)(bt * 16 + sr) * Tsz + tg) * IN_DIM + sc;
        h8 hv0, hv1;
#pragma unroll
        for (int j = 0; j < 8; j++) hv0[j] = (f16)xp[j];
#pragma unroll
        for (int j = 0; j < 8; j++) hv1[j] = (f16)xp[8 + j];
        *(h8*)(stg + sr * 136 + sc) = hv0;
        *(h8*)(stg + sr * 136 + sc + 8) = hv1;
      }
      __syncthreads();
      h8 A[4];
#pragma unroll
      for (int kt = 0; kt < 4; kt++)
        A[kt] = *(const h8*)(stg + col * 136 + kt * 32 + q * 8);
#pragma unroll
      for (int nt = 0; nt < 10; nt++) {
        float b = bias[nt];
        f4 acc = {b, b, b, b};
#pragma unroll
        for (int kt = 0; kt < 4; kt++) acc = MFMA(A[kt], Bf[nt][kt], acc);
        h4 o;
#pragma unroll
        for (int rr = 0; rr < 4; rr++) o[rr] = (f16)acc[rr];
        *(h4*)(XU0 + ((size_t)mt * NT0 + w * 10 + nt) * 256 + lane * 4) = o;
      }
      __syncthreads();
    }
  }
}

// ------- r0 one step: consume xu (t), reload xu for t+2 (depth-2 pipeline) -----------
__device__ __forceinline__ void r0_step(
    const f16* br, f16* bw, const f16* __restrict__ XU0, f16* __restrict__ NH0,
    float* __restrict__ out, const h8 (&Bf)[3][5], h4 (&xu)[3],
    int t, int tload, int bt, int g, int lane, int col, int q, int n, bool last) {
  h8 A[5];
#pragma unroll
  for (int kt = 0; kt < 5; kt++)
    A[kt] = *(const h8*)(br + col * S0 + kt * 32 + q * 8);
  f4 acc0 = {(float)xu[0][0], (float)xu[0][1], (float)xu[0][2], (float)xu[0][3]};
  f4 acc1 = {(float)xu[1][0], (float)xu[1][1], (float)xu[1][2], (float)xu[1][3]};
  f4 acc2 = {(float)xu[2][0], (float)xu[2][1], (float)xu[2][2], (float)xu[2][3]};
  size_t mtl = (size_t)tload * NBT + bt;
#pragma unroll
  for (int mat = 0; mat < 3; mat++)
    xu[mat] = *(const h4*)(XU0 + (mtl * NT0 + mat * 10 + g) * 256 + lane * 4);
#pragma unroll
  for (int kt = 0; kt < 5; kt++) {
    acc0 = MFMA(A[kt], Bf[0][kt], acc0);
    acc1 = MFMA(A[kt], Bf[1][kt], acc1);
    acc2 = MFMA(A[kt], Bf[2][kt], acc2);
  }
  int mt = t * NBT + bt;
  f16* nh = NH0 + (size_t)mt * 2560;
#pragma unroll
  for (int r = 0; r < 4; r++) {
    int m = q * 4 + r;
    float h = cfc_h(acc0[r], acc1[r], acc2[r]);
    f16 h16 = (f16)h;
    bw[m * S0 + n] = h16;
    nh[m * 160 + n] = h16;
    if (last && n < Ni) out[YOFF + (size_t)(bt * 16 + m) * 256 + n] = h;
  }
}

// ------- r12 layer1 one step ---------------------------------------------------------
__device__ __forceinline__ void r12l1_step(
    const f16* br, f16* bw, const f16* __restrict__ XU1, float* __restrict__ out,
    const h8 (&Bf)[3][4], h4 (&xu)[3],
    int tload, int bt, int w, int lane, int col, int q, int n, bool last) {
  h8 A[4];
#pragma unroll
  for (int kt = 0; kt < 4; kt++)
    A[kt] = *(const h8*)(br + col * S2 + kt * 32 + q * 8);
  f4 acc0 = {(float)xu[0][0], (float)xu[0][1], (float)xu[0][2], (float)xu[0][3]};
  f4 acc1 = {(float)xu[1][0], (float)xu[1][1], (float)xu[1][2], (float)xu[1][3]};
  f4 acc2 = {(float)xu[2][0], (float)xu[2][1], (float)xu[2][2], (float)xu[2][3]};
  size_t mtl = (size_t)tload * NBT + bt;
#pragma unroll
  for (int mat = 0; mat < 3; mat++)
    xu[mat] = *(const h4*)(XU1 + (mtl * NT1 + mat * 7 + w) * 256 + lane * 4);
#pragma unroll
  for (int kt = 0; kt < 4; kt++) {
    acc0 = MFMA(A[kt], Bf[0][kt], acc0);
    acc1 = MFMA(A[kt], Bf[1][kt], acc1);
    acc2 = MFMA(A[kt], Bf[2][kt], acc2);
  }
#pragma unroll
  for (int r = 0; r < 4; r++) {
    int m = q * 4 + r;
    float h = cfc_h(acc0[r], acc1[r], acc2[r]);
    if (n < Nc) {
      bw[m * S2 + n] = (f16)h;
      if (last) out[YOFF + (size_t)(bt * 16 + m) * 256 + Ni + n] = h;
    }
  }
}

// ------- r12 layer2 one step: reads rb (nh1(t)|h2(t-1)), writes h2(t) into wb --------
__device__ __forceinline__ void r12l2_step(
    const f16* rb, f16* wb, float* __restrict__ out, const h8 (&Bf)[3][4],
    float bn0, float bn1, float bn2, int tg, int bt, int col, int q, bool last) {
  h8 A[4];
#pragma unroll
  for (int kt = 0; kt < 4; kt++)
    A[kt] = *(const h8*)(rb + col * S2 + kt * 32 + q * 8);
  f4 acc0 = {bn0, bn0, bn0, bn0};
  f4 acc1 = {bn1, bn1, bn1, bn1};
  f4 acc2 = {bn2, bn2, bn2, bn2};
#pragma unroll
  for (int kt = 0; kt < 4; kt++) {
    acc0 = MFMA(A[kt], Bf[0][kt], acc0);
    acc1 = MFMA(A[kt], Bf[1][kt], acc1);
    acc2 = MFMA(A[kt], Bf[2][kt], acc2);
  }
#pragma unroll
  for (int r = 0; r < 4; r++) {
    int m = q * 4 + r;
    float h = cfc_h(acc0[r], acc1[r], acc2[r]);
    if (col < Nm) {
      out[((size_t)(bt * 16 + m) * Tsz + tg) * 8 + col] = tanhp_(h);
      wb[m * S2 + Nc + col] = (f16)h;
      if (last) out[YOFF + (size_t)(bt * 16 + m) * 256 + Ni + Nc + col] = h;
    }
  }
}

// ---------------- R: [r0(c) on WGs 0-15 | r12(c-1) on WGs 16-31] ---------------------
__global__ __launch_bounds__(640) void R_kernel(
    const h8* __restrict__ pk,
    const float* __restrict__ c1, const float* __restrict__ c2,
    const float* __restrict__ ca, const float* __restrict__ cb,
    const float* __restrict__ dtp, const f16* __restrict__ XU0,
    const f16* __restrict__ XU1, f16* __restrict__ NH0,
    f16* __restrict__ H0S, f16* __restrict__ H12S, float* __restrict__ out, int c) {
  __shared__ __align__(16) char smem[2 * 16 * S0 * 2];  // union: r0 buf / r12 buf
  int tid = threadIdx.x;
  int g = tid >> 6, lane = tid & 63, col = lane & 15, q = lane >> 4;
  int wg = blockIdx.x;

  if (wg < NBT) {  // ================= r0, chunk c =================
    if (c >= NCH) return;
    f16(*buf)[16 * S0] = (f16(*)[16 * S0])smem;
    int bt = wg;
    int n = g * 16 + col;                      // output neuron (0..159, valid <149)
    h8 Bf[3][5];                               // recurrent weights, resident across t-loop
#pragma unroll
    for (int mat = 0; mat < 3; mat++)
#pragma unroll
      for (int kt = 0; kt < 5; kt++)
        Bf[mat][kt] = pk[OFF_R0 + ((g * 3 + mat) * 5 + kt) * 64 + lane];

    for (int idx = tid; idx < 16 * S0; idx += 640) {
      buf[0][idx] = (c == 0) ? (f16)0.f : H0S[(size_t)bt * 16 * S0 + idx];
      buf[1][idx] = (f16)0.f;
    }
    __syncthreads();

    h4 xuA[3], xuB[3];                         // depth-2 prefetch register sets
#pragma unroll
    for (int mat = 0; mat < 3; mat++) {
      xuA[mat] = *(const h4*)(XU0 + ((size_t)bt * NT0 + mat * 10 + g) * 256 + lane * 4);
      xuB[mat] =
          *(const h4*)(XU0 + ((size_t)(NBT + bt) * NT0 + mat * 10 + g) * 256 + lane * 4);
    }

    for (int t = 0; t < TC; t += 2) {
      bool lastA = (c == NCH - 1) && (t == TC - 1);       // never true (t even)
      int tlA = (t + 2 < TC) ? t + 2 : t;
      r0_step(buf[0], buf[1], XU0, NH0, out, Bf, xuA, t, tlA, bt, g, lane, col, q, n,
              lastA);
      RAW_BAR();
      bool lastB = (c == NCH - 1) && (t + 1 == TC - 1);
      int tlB = (t + 3 < TC) ? t + 3 : t + 1;
      r0_step(buf[1], buf[0], XU0, NH0, out, Bf, xuB, t + 1, tlB, bt, g, lane, col, q,
              n, lastB);
      RAW_BAR();
    }
    for (int idx = tid; idx < 16 * S0; idx += 640)
      H0S[(size_t)bt * 16 * S0 + idx] = buf[0][idx];

  } else {  // ================= r12, chunk cc = c-1 =================
    int cc = c - 1;
    if (cc < 0) return;
    f16(*buf)[16 * S2] = (f16(*)[16 * S2])smem;
    int bt = wg - NBT;
    int w = g;                                 // wave id 0..9 (8,9 idle)
    float ts = dtp[0];
    h8 Bf[3][4];
    float bn0 = 0.f, bn1 = 0.f, bn2 = 0.f;
    int n = w * 16 + col;
    if (w < 7) {
#pragma unroll
      for (int mat = 0; mat < 3; mat++)
#pragma unroll
        for (int kt = 0; kt < 4; kt++)
          Bf[mat][kt] = pk[OFF_R12A + ((w * 3 + mat) * 4 + kt) * 64 + lane];
    } else if (w == 7) {
#pragma unroll
      for (int mat = 0; mat < 3; mat++)
#pragma unroll
        for (int kt = 0; kt < 4; kt++)
          Bf[mat][kt] = pk[OFF_R12B + (mat * 4 + kt) * 64 + lane];
      bn0 = (col < Nm) ? -2.f * c1[col] : 0.f;
      bn1 = (col < Nm) ? -2.f * c2[col] : 0.f;
      bn2 = (col < Nm) ? -(ts * ca[col] + cb[col]) : 0.f;
    }
    for (int idx = tid; idx < 2 * 16 * S2; idx += 640)
      ((f16*)buf)[idx] = (cc == 0) ? (f16)0.f : H12S[(size_t)bt * 2 * 16 * S2 + idx];
    __syncthreads();

    h4 xuA[3], xuB[3];
    if (w < 7) {
#pragma unroll
      for (int mat = 0; mat < 3; mat++) {
        xuA[mat] =
            *(const h4*)(XU1 + ((size_t)bt * NT1 + mat * 7 + w) * 256 + lane * 4);
        xuB[mat] = *(const h4*)(XU1 +
                                ((size_t)(NBT + bt) * NT1 + mat * 7 + w) * 256 +
                                lane * 4);
      }
    }

    for (int t = 0; t < TC; t += 2) {
      if (w < 7) {
        int tlA = (t + 2 < TC) ? t + 2 : t;
        bool lastA = (cc == NCH - 1) && (t == TC - 1);    // never true
        r12l1_step(buf[0], buf[1], XU1, out, Bf, xuA, tlA, bt, w, lane, col, q, n,
                   lastA);
      }
      RAW_BAR();
      if (w == 7)
        r12l2_step(buf[1], buf[0], out, Bf, bn0, bn1, bn2, cc * TC + t, bt, col, q,
                   false);
      if (w < 7) {
        int tlB = (t + 3 < TC) ? t + 3 : t + 1;
        bool lastB = (cc == NCH - 1) && (t + 1 == TC - 1);
        r12l1_step(buf[1], buf[0], XU1, out, Bf, xuB, tlB, bt, w, lane, col, q, n,
                   lastB);
      }
      RAW_BAR();
      if (w == 7)
        r12l2_step(buf[0], buf[1], out, Bf, bn0, bn1, bn2, cc * TC + t + 1, bt, col, q,
                   (cc == NCH - 1) && (t + 1 == TC - 1));
    }
    __syncthreads();
    for (int idx = tid; idx < 2 * 16 * S2; idx += 640)
      H12S[(size_t)bt * 2 * 16 * S2 + idx] = ((f16*)buf)[idx];
  }
}

extern "C" void kernel_launch(void* const* d_in, const int* in_sizes, int n_in,
                              void* d_out, int out_size, void* d_ws, size_t ws_size,
                              hipStream_t stream) {
  const float* w1_0 = (const float*)d_in[0];
  const float* w2_0 = (const float*)d_in[1];
  const float* wa_0 = (const float*)d_in[2];
  const float* wb_0 = (const float*)d_in[3];
  const float* b1_0 = (const float*)d_in[4];
  const float* b2_0 = (const float*)d_in[5];
  const float* ba_0 = (const float*)d_in[6];
  const float* bb_0 = (const float*)d_in[7];
  const int* m0 = (const int*)d_in[8];
  const float* w1_1 = (const float*)d_in[9];
  const float* w2_1 = (const float*)d_in[10];
  const float* wa_1 = (const float*)d_in[11];
  const float* wb_1 = (const float*)d_in[12];
  const float* b1_1 = (const float*)d_in[13];
  const float* b2_1 = (const float*)d_in[14];
  const float* ba_1 = (const float*)d_in[15];
  const float* bb_1 = (const float*)d_in[16];
  const int* m1 = (const int*)d_in[17];
  const float* w1_2 = (const float*)d_in[18];
  const float* w2_2 = (const float*)d_in[19];
  const float* wa_2 = (const float*)d_in[20];
  const float* wb_2 = (const float*)d_in[21];
  const float* c1 = (const float*)d_in[22];
  const float* c2 = (const float*)d_in[23];
  const float* ca = (const float*)d_in[24];
  const float* cb = (const float*)d_in[25];
  const int* m2 = (const int*)d_in[26];
  const float* x = (const float*)d_in[27];
  const float* dt = (const float*)d_in[28];
  float* out = (float*)d_out;

  f16* XU0 = (f16*)d_ws;
  f16* NH0 = XU0 + XU0_HALVES;
  f16* XU1 = NH0 + NH0_HALVES;
  f16* H0S = XU1 + XU1_HALVES;
  f16* H12S = H0S + H0S_HALVES;
  f16* PK = H12S + H12S_HALVES;
  const h8* pk = (const h8*)PK;

  pack_kernel<<<(NFRAG + 255) / 256, 256, 0, stream>>>(
      w1_0, w2_0, wa_0, wb_0, m0, w1_1, w2_1, wa_1, wb_1, m1,
      w1_2, w2_2, wa_2, wb_2, m2, dt, PK);

  // prologue: x0(0)
  X_kernel<<<1024, 192, 0, stream>>>(pk, x, NH0, XU0, XU1, b1_0, b2_0, ba_0, bb_0,
                                     b1_1, b2_1, ba_1, bb_1, dt, -1);

  for (int c = 0; c <= NCH; c++) {
    R_kernel<<<32, 640, 0, stream>>>(pk, c1, c2, ca, cb, dt, XU0, XU1, NH0, H0S,
                                     H12S, out, c);
    if (c < NCH)
      X_kernel<<<1024, 192, 0, stream>>>(pk, x, NH0, XU0, XU1, b1_0, b2_0, ba_0,
                                         bb_0, b1_1, b2_1, ba_1, bb_1, dt, c);
  }
}